// Round 1
// baseline (4706.570 us; speedup 1.0000x reference)
//
#include <hip/hip_runtime.h>
#include <hip/hip_bf16.h>

#define N_NODES 50000
#define N_EDGES 800000
#define IN_DIM 128
#define HID 256
#define N_LAYERS 8
#define HEADS 8
#define DH 32
#define OUT_DIM 40
#define SCALING 0.17677669529663687f

// ---------------- CSR build (by dst) ----------------
__global__ void hist_kernel(const int* __restrict__ dst, int* __restrict__ cnt, int E) {
    int e = blockIdx.x * blockDim.x + threadIdx.x;
    if (e < E) atomicAdd(&cnt[dst[e]], 1);
}

__global__ __launch_bounds__(1024) void scan_kernel(const int* __restrict__ cnt,
                                                    int* __restrict__ row_off, int n) {
    __shared__ int buf[1024];
    __shared__ int carry_s;
    int tid = threadIdx.x;
    if (tid == 0) carry_s = 0;
    __syncthreads();
    for (int base = 0; base < n; base += 1024) {
        int i = base + tid;
        int x = (i < n) ? cnt[i] : 0;
        buf[tid] = x;
        __syncthreads();
        for (int off = 1; off < 1024; off <<= 1) {
            int y = (tid >= off) ? buf[tid - off] : 0;
            __syncthreads();
            buf[tid] += y;
            __syncthreads();
        }
        int carry = carry_s;
        if (i < n) row_off[i] = carry + buf[tid] - x;   // exclusive
        int total = buf[1023];
        __syncthreads();
        if (tid == 0) carry_s = carry + total;
        __syncthreads();
    }
    if (tid == 0) row_off[n] = carry_s;
}

__global__ void scatter_kernel(const int* __restrict__ src, const int* __restrict__ dst,
                               const int* __restrict__ row_off, int* __restrict__ cur,
                               int* __restrict__ csr_src, int E) {
    int e = blockIdx.x * blockDim.x + threadIdx.x;
    if (e < E) {
        int d = dst[e];
        int pos = row_off[d] + atomicAdd(&cur[d], 1);
        csr_src[pos] = src[e];
    }
}

// ---------------- fp32 GEMM: C = (A[M,K] @ B[K,Nc] + bias) * scale ----------------
// block 256 threads, tile 128x64, BK=16, per-thread 8x4
__global__ __launch_bounds__(256) void gemm_bias_kernel(
        const float* __restrict__ A, const float* __restrict__ B,
        const float* __restrict__ bias, float* __restrict__ C,
        int M, int Nc, int K, float scale) {
    __shared__ float As[16][128 + 4];
    __shared__ float Bs[16][64 + 4];
    const int tid = threadIdx.x;
    const int tx = tid & 15;   // col group (4 cols)
    const int ty = tid >> 4;   // row group (8 rows)
    const int row0 = blockIdx.y * 128;
    const int col0 = blockIdx.x * 64;
    float acc[8][4];
#pragma unroll
    for (int i = 0; i < 8; ++i)
#pragma unroll
        for (int j = 0; j < 4; ++j) acc[i][j] = 0.f;

    for (int k0 = 0; k0 < K; k0 += 16) {
        // A tile 128x16 = 2048 floats -> 2 float4 per thread (store transposed)
#pragma unroll
        for (int u = 0; u < 2; ++u) {
            int unit = tid + u * 256;
            int r = unit >> 2;
            int c = (unit & 3) << 2;
            int gr = row0 + r;
            float4 val = make_float4(0.f, 0.f, 0.f, 0.f);
            if (gr < M) val = *reinterpret_cast<const float4*>(&A[(size_t)gr * K + k0 + c]);
            As[c + 0][r] = val.x;
            As[c + 1][r] = val.y;
            As[c + 2][r] = val.z;
            As[c + 3][r] = val.w;
        }
        // B tile 16x64 = 1024 floats -> 1 float4 per thread
        {
            int r = tid >> 4;
            int c = (tid & 15) << 2;
            int gc = col0 + c;
            const float* Brow = &B[(size_t)(k0 + r) * Nc];
            float4 val = make_float4(0.f, 0.f, 0.f, 0.f);
            if (gc + 3 < Nc) {
                val = *reinterpret_cast<const float4*>(&Brow[gc]);
            } else {
                if (gc + 0 < Nc) val.x = Brow[gc + 0];
                if (gc + 1 < Nc) val.y = Brow[gc + 1];
                if (gc + 2 < Nc) val.z = Brow[gc + 2];
            }
            Bs[r][c + 0] = val.x;
            Bs[r][c + 1] = val.y;
            Bs[r][c + 2] = val.z;
            Bs[r][c + 3] = val.w;
        }
        __syncthreads();
#pragma unroll
        for (int kk = 0; kk < 16; ++kk) {
            float a[8], b[4];
#pragma unroll
            for (int i = 0; i < 8; ++i) a[i] = As[kk][ty * 8 + i];
#pragma unroll
            for (int j = 0; j < 4; ++j) b[j] = Bs[kk][tx * 4 + j];
#pragma unroll
            for (int i = 0; i < 8; ++i)
#pragma unroll
                for (int j = 0; j < 4; ++j) acc[i][j] = fmaf(a[i], b[j], acc[i][j]);
        }
        __syncthreads();
    }
#pragma unroll
    for (int i = 0; i < 8; ++i) {
        int gr = row0 + ty * 8 + i;
        if (gr >= M) continue;
#pragma unroll
        for (int j = 0; j < 4; ++j) {
            int gc = col0 + tx * 4 + j;
            if (gc < Nc) C[(size_t)gr * Nc + gc] = (acc[i][j] + bias[gc]) * scale;
        }
    }
}

// ---------------- fused SDDMM + segment-softmax + SpMM ----------------
// one 64-lane wave per dst node; lane -> head = lane>>3, dims (lane&7)*4 .. +4
__global__ __launch_bounds__(256) void attn_kernel(
        const float* __restrict__ q, const float* __restrict__ kmat,
        const float* __restrict__ vmat, const int* __restrict__ row_off,
        const int* __restrict__ csr_src, float* __restrict__ h_out, int n) {
    int wave = threadIdx.x >> 6;
    int lane = threadIdx.x & 63;
    int node = blockIdx.x * 4 + wave;
    if (node >= n) return;
    float4 qv = *reinterpret_cast<const float4*>(&q[(size_t)node * HID + lane * 4]);
    float4 acc = make_float4(0.f, 0.f, 0.f, 0.f);
    float m = -INFINITY, s = 0.f;
    int beg = row_off[node], end = row_off[node + 1];
    for (int idx = beg; idx < end; ++idx) {
        int sn = csr_src[idx];
        const float4 kv = *reinterpret_cast<const float4*>(&kmat[(size_t)sn * HID + lane * 4]);
        float d = qv.x * kv.x + qv.y * kv.y + qv.z * kv.z + qv.w * kv.w;
        d += __shfl_xor(d, 1);
        d += __shfl_xor(d, 2);
        d += __shfl_xor(d, 4);   // per-head score broadcast across the 8-lane head group
        float mnew = fmaxf(m, d);
        float c = __expf(m - mnew);
        float p = __expf(d - mnew);
        s = s * c + p;
        m = mnew;
        const float4 vv = *reinterpret_cast<const float4*>(&vmat[(size_t)sn * HID + lane * 4]);
        acc.x = acc.x * c + p * vv.x;
        acc.y = acc.y * c + p * vv.y;
        acc.z = acc.z * c + p * vv.z;
        acc.w = acc.w * c + p * vv.w;
    }
    float inv = (s > 0.f) ? 1.f / s : 0.f;
    acc.x *= inv; acc.y *= inv; acc.z *= inv; acc.w *= inv;
    *reinterpret_cast<float4*>(&h_out[(size_t)node * HID + lane * 4]) = acc;
}

extern "C" void kernel_launch(void* const* d_in, const int* in_sizes, int n_in,
                              void* d_out, int out_size, void* d_ws, size_t ws_size,
                              hipStream_t stream) {
    const float* X    = (const float*)d_in[0];
    const int*   src  = (const int*)d_in[1];
    const int*   dst  = (const int*)d_in[2];
    const float* Win  = (const float*)d_in[3];
    const float* bin_ = (const float*)d_in[4];
    const float* Wq   = (const float*)d_in[5];
    const float* Wk   = (const float*)d_in[6];
    const float* Wv   = (const float*)d_in[7];
    const float* bq   = (const float*)d_in[8];
    const float* bk   = (const float*)d_in[9];
    const float* bv   = (const float*)d_in[10];
    const float* Wout = (const float*)d_in[11];
    const float* bout = (const float*)d_in[12];
    float* out = (float*)d_out;

    char* ws = (char*)d_ws;
    size_t off = 0;
    auto alloc = [&](size_t bytes) -> void* {
        void* p = ws + off;
        off = (off + bytes + 255) & ~(size_t)255;
        return p;
    };
    float* h  = (float*)alloc(sizeof(float) * N_NODES * HID);
    float* qb = (float*)alloc(sizeof(float) * N_NODES * HID);
    float* kb = (float*)alloc(sizeof(float) * N_NODES * HID);
    float* vb = (float*)alloc(sizeof(float) * N_NODES * HID);
    int* cnt     = (int*)alloc(sizeof(int) * N_NODES);
    int* row_off = (int*)alloc(sizeof(int) * (N_NODES + 1));
    int* csr_src = (int*)alloc(sizeof(int) * N_EDGES);

    // CSR build (graph is layer-invariant; built once per launch)
    hipMemsetAsync(cnt, 0, sizeof(int) * N_NODES, stream);
    hist_kernel<<<(N_EDGES + 255) / 256, 256, 0, stream>>>(dst, cnt, N_EDGES);
    scan_kernel<<<1, 1024, 0, stream>>>(cnt, row_off, N_NODES);
    hipMemsetAsync(cnt, 0, sizeof(int) * N_NODES, stream);
    scatter_kernel<<<(N_EDGES + 255) / 256, 256, 0, stream>>>(src, dst, row_off, cnt, csr_src, N_EDGES);

    dim3 blk(256);
    dim3 grid_hid(HID / 64, (N_NODES + 127) / 128);
    // in_proj
    gemm_bias_kernel<<<grid_hid, blk, 0, stream>>>(X, Win, bin_, h, N_NODES, HID, IN_DIM, 1.f);

    for (int l = 0; l < N_LAYERS; ++l) {
        const float* wq = Wq + (size_t)l * HID * HID;
        const float* wk = Wk + (size_t)l * HID * HID;
        const float* wv = Wv + (size_t)l * HID * HID;
        gemm_bias_kernel<<<grid_hid, blk, 0, stream>>>(h, wq, bq + l * HID, qb, N_NODES, HID, HID, SCALING);
        gemm_bias_kernel<<<grid_hid, blk, 0, stream>>>(h, wk, bk + l * HID, kb, N_NODES, HID, HID, 1.f);
        gemm_bias_kernel<<<grid_hid, blk, 0, stream>>>(h, wv, bv + l * HID, vb, N_NODES, HID, HID, 1.f);
        attn_kernel<<<(N_NODES + 3) / 4, blk, 0, stream>>>(qb, kb, vb, row_off, csr_src, h, N_NODES);
    }
    // out_proj
    dim3 grid_out((OUT_DIM + 63) / 64, (N_NODES + 127) / 128);
    gemm_bias_kernel<<<grid_out, blk, 0, stream>>>(h, Wout, bout, out, N_NODES, OUT_DIM, HID, 1.f);
}

// Round 4
// 2537.386 us; speedup vs baseline: 1.8549x; 1.8549x over previous
//
#include <hip/hip_runtime.h>
#include <hip/hip_bf16.h>
#include <hip/hip_fp16.h>

#define N_NODES 50000
#define MPAD    50048            // 391 * 128
#define N_EDGES 800000
#define IN_DIM  128
#define HID     256
#define N_LAYERS 8
#define OUT_DIM 40
#define SCALING 0.17677669529663687f

typedef __attribute__((ext_vector_type(8))) short bf16x8;
typedef __attribute__((ext_vector_type(4))) float f32x4;

__device__ __forceinline__ unsigned short f2bf(float x) {
    unsigned u = __float_as_uint(x);
    u += 0x7FFFu + ((u >> 16) & 1u);
    return (unsigned short)(u >> 16);
}
__device__ __forceinline__ float bf2f(unsigned short h) {
    return __uint_as_float(((unsigned)h) << 16);
}

__device__ __forceinline__ void gload_lds16(const void* g, void* l) {
    __builtin_amdgcn_global_load_lds(
        (__attribute__((address_space(1))) const unsigned int*)g,
        (__attribute__((address_space(3))) unsigned int*)l, 16, 0, 0);
}

// ---------------- CSR build (by dst) ----------------
__global__ void hist_kernel(const int* __restrict__ dst, int* __restrict__ cnt, int E) {
    int e = blockIdx.x * blockDim.x + threadIdx.x;
    if (e < E) atomicAdd(&cnt[dst[e]], 1);
}

__global__ __launch_bounds__(1024) void scan_kernel(const int* __restrict__ cnt,
                                                    int* __restrict__ row_off, int n) {
    __shared__ int buf[1024];
    __shared__ int carry_s;
    int tid = threadIdx.x;
    if (tid == 0) carry_s = 0;
    __syncthreads();
    for (int base = 0; base < n; base += 1024) {
        int i = base + tid;
        int x = (i < n) ? cnt[i] : 0;
        buf[tid] = x;
        __syncthreads();
        for (int off = 1; off < 1024; off <<= 1) {
            int y = (tid >= off) ? buf[tid - off] : 0;
            __syncthreads();
            buf[tid] += y;
            __syncthreads();
        }
        int carry = carry_s;
        if (i < n) row_off[i] = carry + buf[tid] - x;   // exclusive
        int total = buf[1023];
        __syncthreads();
        if (tid == 0) carry_s = carry + total;
        __syncthreads();
    }
    if (tid == 0) row_off[n] = carry_s;
}

__global__ void scatter_kernel(const int* __restrict__ src, const int* __restrict__ dst,
                               const int* __restrict__ row_off, int* __restrict__ cur,
                               int* __restrict__ csr_src, int E) {
    int e = blockIdx.x * blockDim.x + threadIdx.x;
    if (e < E) {
        int d = dst[e];
        int pos = row_off[d] + atomicAdd(&cur[d], 1);
        csr_src[pos] = src[e];
    }
}

// ---------------- conversion kernels ----------------
// W [slabs][K][Nc] fp32  ->  hi/lo bf16 at [slabs][Npad][K]  (transposed, padded)
__global__ void wsplit_kernel(const float* __restrict__ W, unsigned short* __restrict__ hi,
                              unsigned short* __restrict__ lo, int K, int Nc, int Npad, int total) {
    int i = blockIdx.x * blockDim.x + threadIdx.x;
    if (i >= total) return;
    int k = i % K;
    int t = i / K;
    int n = t % Npad;
    int s = t / Npad;
    float v = (n < Nc) ? W[((size_t)s * K + k) * Nc + n] : 0.f;
    unsigned short h = f2bf(v);
    hi[i] = h;
    lo[i] = f2bf(v - bf2f(h));
}

// X [N_NODES][IN] fp32 -> hi/lo bf16 [MPAD][IN] (pad rows zero)
__global__ void xsplit_kernel(const float* __restrict__ X, unsigned short* __restrict__ hi,
                              unsigned short* __restrict__ lo) {
    int i = blockIdx.x * blockDim.x + threadIdx.x;
    if (i >= MPAD * IN_DIM) return;
    int r = i / IN_DIM;
    float v = (r < N_NODES) ? X[i] : 0.f;
    unsigned short h = f2bf(v);
    hi[i] = h;
    lo[i] = f2bf(v - bf2f(h));
}

// ---------------- split-bf16 MFMA GEMM ----------------
// C[M, Nc] = (A @ B + bias) * scale, A = Ahi+Alo [MPAD][K] bf16, B^T = Bhi+Blo [Npad][K] bf16
// block: 256 threads (4 waves), tile 128x128, BK=32.
// OUTMODE: 0 = fp32, 1 = fp16, 2 = bf16 hi/lo pair (Cv=hi, C1v=lo)
template<int OUTMODE>
__global__ __launch_bounds__(256) void gemm_mfma(
        const unsigned short* __restrict__ Ahi, const unsigned short* __restrict__ Alo,
        const unsigned short* __restrict__ Bhi, const unsigned short* __restrict__ Blo,
        const float* __restrict__ bias, void* __restrict__ Cv, void* __restrict__ C1v,
        int K, int Mstore, int Nstore, int ldC, float scale) {
    __shared__ __align__(16) unsigned short lds[4 * 4096];   // Ahi, Alo, Bhi, Blo tiles (8KB each)
    unsigned short* ldsAhi = lds;
    unsigned short* ldsAlo = lds + 4096;
    unsigned short* ldsBhi = lds + 8192;
    unsigned short* ldsBlo = lds + 12288;

    const int tid  = threadIdx.x;
    const int lane = tid & 63;
    const int wave = tid >> 6;
    const int row0 = blockIdx.y * 128;
    const int n0   = blockIdx.x * 128;

    // staging: tile is [128 rows][32 k] bf16 = 512 16B-chunks, linear in LDS.
    // chunk p holds global k-chunk (p&3) ^ swz(row) with swz(r) = (r&3)^((r>>2)&3)  (involution)
    const int p0 = wave * 64 + lane;
    const int p1 = p0 + 256;
    auto srcoff = [&](int p, int grow0) -> size_t {
        int row = p >> 2, cir = p & 3;
        int sw  = (row & 3) ^ ((row >> 2) & 3);
        int sc  = cir ^ sw;
        return (size_t)(grow0 + row) * K + sc * 8;   // element offset
    };
    const size_t offA0 = srcoff(p0, row0), offA1 = srcoff(p1, row0);
    const size_t offB0 = srcoff(p0, n0),   offB1 = srcoff(p1, n0);
    const int d0 = wave * 512;          // ushort offset of this wave's first 1KB dest
    const int d1 = 2048 + wave * 512;   // second 1KB dest

    // fragment read offsets (bytes in tile), swizzled to match
    const int mh = (wave >> 1) * 64;
    const int nh = (wave & 1) * 64;
    int aoff[4], boff[4];
#pragma unroll
    for (int f = 0; f < 4; ++f) {
        int ra = mh + f * 16 + (lane & 15);
        int ca = (lane >> 4) ^ ((ra & 3) ^ ((ra >> 2) & 3));
        aoff[f] = ra * 64 + ca * 16;
        int rb = nh + f * 16 + (lane & 15);
        int cb = (lane >> 4) ^ ((rb & 3) ^ ((rb >> 2) & 3));
        boff[f] = rb * 64 + cb * 16;
    }

    f32x4 acc[4][4];
#pragma unroll
    for (int i = 0; i < 4; ++i)
#pragma unroll
        for (int j = 0; j < 4; ++j) acc[i][j] = {0.f, 0.f, 0.f, 0.f};

    for (int k0 = 0; k0 < K; k0 += 32) {
        gload_lds16(Ahi + offA0 + k0, ldsAhi + d0);
        gload_lds16(Ahi + offA1 + k0, ldsAhi + d1);
        gload_lds16(Alo + offA0 + k0, ldsAlo + d0);
        gload_lds16(Alo + offA1 + k0, ldsAlo + d1);
        gload_lds16(Bhi + offB0 + k0, ldsBhi + d0);
        gload_lds16(Bhi + offB1 + k0, ldsBhi + d1);
        gload_lds16(Blo + offB0 + k0, ldsBlo + d0);
        gload_lds16(Blo + offB1 + k0, ldsBlo + d1);
        __syncthreads();
        bf16x8 ah[4], al[4];
#pragma unroll
        for (int i = 0; i < 4; ++i) {
            ah[i] = *reinterpret_cast<const bf16x8*>(reinterpret_cast<const char*>(ldsAhi) + aoff[i]);
            al[i] = *reinterpret_cast<const bf16x8*>(reinterpret_cast<const char*>(ldsAlo) + aoff[i]);
        }
#pragma unroll
        for (int j = 0; j < 4; ++j) {
            bf16x8 bh = *reinterpret_cast<const bf16x8*>(reinterpret_cast<const char*>(ldsBhi) + boff[j]);
            bf16x8 bl = *reinterpret_cast<const bf16x8*>(reinterpret_cast<const char*>(ldsBlo) + boff[j]);
#pragma unroll
            for (int i = 0; i < 4; ++i) {
                acc[i][j] = __builtin_amdgcn_mfma_f32_16x16x32_bf16(ah[i], bh, acc[i][j], 0, 0, 0);
                acc[i][j] = __builtin_amdgcn_mfma_f32_16x16x32_bf16(ah[i], bl, acc[i][j], 0, 0, 0);
                acc[i][j] = __builtin_amdgcn_mfma_f32_16x16x32_bf16(al[i], bh, acc[i][j], 0, 0, 0);
            }
        }
        __syncthreads();
    }

    const int fq = lane >> 4;
    const int fr = lane & 15;
#pragma unroll
    for (int i = 0; i < 4; ++i) {
#pragma unroll
        for (int j = 0; j < 4; ++j) {
#pragma unroll
            for (int r = 0; r < 4; ++r) {
                int m = row0 + mh + i * 16 + fq * 4 + r;
                int n = n0 + nh + j * 16 + fr;
                if (m < Mstore && n < Nstore) {
                    float o = (acc[i][j][r] + bias[n]) * scale;
                    if (OUTMODE == 0) {
                        ((float*)Cv)[(size_t)m * ldC + n] = o;
                    } else if (OUTMODE == 1) {
                        ((__half*)Cv)[(size_t)m * ldC + n] = __float2half(o);
                    } else {
                        unsigned short h = f2bf(o);
                        ((unsigned short*)Cv)[(size_t)m * ldC + n] = h;
                        ((unsigned short*)C1v)[(size_t)m * ldC + n] = f2bf(o - bf2f(h));
                    }
                }
            }
        }
    }
}

// ---------------- fused SDDMM + segment-softmax + SpMM ----------------
// one wave per dst node; lane -> head = lane>>3, dims (lane&7)*4 .. +4 (fp16 q/k/v)
__global__ __launch_bounds__(256) void attn_kernel(
        const __half* __restrict__ q, const __half* __restrict__ kmat,
        const __half* __restrict__ vmat, const int* __restrict__ row_off,
        const int* __restrict__ csr_src,
        unsigned short* __restrict__ h_hi, unsigned short* __restrict__ h_lo, int n) {
    int wave = threadIdx.x >> 6;
    int lane = threadIdx.x & 63;
    int node = blockIdx.x * 4 + wave;
    if (node >= n) return;
    float4 qv;
    {
        float2 raw = *reinterpret_cast<const float2*>(&q[(size_t)node * HID + lane * 4]);
        const __half2* h2 = reinterpret_cast<const __half2*>(&raw);
        float2 a = __half22float2(h2[0]), b = __half22float2(h2[1]);
        qv = make_float4(a.x, a.y, b.x, b.y);
    }
    float4 acc = make_float4(0.f, 0.f, 0.f, 0.f);
    float m = -INFINITY, s = 0.f;
    int beg = row_off[node], end = row_off[node + 1];
    for (int idx = beg; idx < end; ++idx) {
        int sn = csr_src[idx];
        float2 kraw = *reinterpret_cast<const float2*>(&kmat[(size_t)sn * HID + lane * 4]);
        const __half2* kh = reinterpret_cast<const __half2*>(&kraw);
        float2 k01 = __half22float2(kh[0]), k23 = __half22float2(kh[1]);
        float d = qv.x * k01.x + qv.y * k01.y + qv.z * k23.x + qv.w * k23.y;
        d += __shfl_xor(d, 1);
        d += __shfl_xor(d, 2);
        d += __shfl_xor(d, 4);   // per-head score across the 8-lane head group
        float mnew = fmaxf(m, d);
        float c = __expf(m - mnew);
        float p = __expf(d - mnew);
        s = s * c + p;
        m = mnew;
        float2 vraw = *reinterpret_cast<const float2*>(&vmat[(size_t)sn * HID + lane * 4]);
        const __half2* vh = reinterpret_cast<const __half2*>(&vraw);
        float2 v01 = __half22float2(vh[0]), v23 = __half22float2(vh[1]);
        acc.x = acc.x * c + p * v01.x;
        acc.y = acc.y * c + p * v01.y;
        acc.z = acc.z * c + p * v23.x;
        acc.w = acc.w * c + p * v23.y;
    }
    float inv = (s > 0.f) ? 1.f / s : 0.f;
    float o0 = acc.x * inv, o1 = acc.y * inv, o2 = acc.z * inv, o3 = acc.w * inv;
    ushort4 hv, lv;
    hv.x = f2bf(o0); lv.x = f2bf(o0 - bf2f(hv.x));
    hv.y = f2bf(o1); lv.y = f2bf(o1 - bf2f(hv.y));
    hv.z = f2bf(o2); lv.z = f2bf(o2 - bf2f(hv.z));
    hv.w = f2bf(o3); lv.w = f2bf(o3 - bf2f(hv.w));
    *reinterpret_cast<ushort4*>(&h_hi[(size_t)node * HID + lane * 4]) = hv;
    *reinterpret_cast<ushort4*>(&h_lo[(size_t)node * HID + lane * 4]) = lv;
}

extern "C" void kernel_launch(void* const* d_in, const int* in_sizes, int n_in,
                              void* d_out, int out_size, void* d_ws, size_t ws_size,
                              hipStream_t stream) {
    const float* X    = (const float*)d_in[0];
    const int*   src  = (const int*)d_in[1];
    const int*   dst  = (const int*)d_in[2];
    const float* Win  = (const float*)d_in[3];
    const float* bin_ = (const float*)d_in[4];
    const float* Wq   = (const float*)d_in[5];
    const float* Wk   = (const float*)d_in[6];
    const float* Wv   = (const float*)d_in[7];
    const float* bq   = (const float*)d_in[8];
    const float* bk   = (const float*)d_in[9];
    const float* bv   = (const float*)d_in[10];
    const float* Wout = (const float*)d_in[11];
    const float* bout = (const float*)d_in[12];
    float* out = (float*)d_out;

    char* ws = (char*)d_ws;
    size_t off = 0;
    auto alloc = [&](size_t bytes) -> void* {
        void* p = ws + off;
        off = (off + bytes + 255) & ~(size_t)255;
        return p;
    };
    unsigned short* h_hi = (unsigned short*)alloc((size_t)MPAD * HID * 2);
    unsigned short* h_lo = (unsigned short*)alloc((size_t)MPAD * HID * 2);
    __half* qf = (__half*)alloc((size_t)MPAD * HID * 2);
    __half* kf = (__half*)alloc((size_t)MPAD * HID * 2);
    __half* vf = (__half*)alloc((size_t)MPAD * HID * 2);
    unsigned short* Xhi = (unsigned short*)alloc((size_t)MPAD * IN_DIM * 2);
    unsigned short* Xlo = (unsigned short*)alloc((size_t)MPAD * IN_DIM * 2);
    unsigned short* Wqt_hi = (unsigned short*)alloc((size_t)N_LAYERS * HID * HID * 2);
    unsigned short* Wqt_lo = (unsigned short*)alloc((size_t)N_LAYERS * HID * HID * 2);
    unsigned short* Wkt_hi = (unsigned short*)alloc((size_t)N_LAYERS * HID * HID * 2);
    unsigned short* Wkt_lo = (unsigned short*)alloc((size_t)N_LAYERS * HID * HID * 2);
    unsigned short* Wvt_hi = (unsigned short*)alloc((size_t)N_LAYERS * HID * HID * 2);
    unsigned short* Wvt_lo = (unsigned short*)alloc((size_t)N_LAYERS * HID * HID * 2);
    unsigned short* Wint_hi = (unsigned short*)alloc((size_t)HID * IN_DIM * 2);
    unsigned short* Wint_lo = (unsigned short*)alloc((size_t)HID * IN_DIM * 2);
    unsigned short* Wot_hi = (unsigned short*)alloc((size_t)128 * HID * 2);
    unsigned short* Wot_lo = (unsigned short*)alloc((size_t)128 * HID * 2);
    int* cnt     = (int*)alloc(sizeof(int) * N_NODES);
    int* row_off = (int*)alloc(sizeof(int) * (N_NODES + 1));
    int* csr_src = (int*)alloc(sizeof(int) * N_EDGES);

    // CSR build
    hipMemsetAsync(cnt, 0, sizeof(int) * N_NODES, stream);
    hist_kernel<<<(N_EDGES + 255) / 256, 256, 0, stream>>>(dst, cnt, N_EDGES);
    scan_kernel<<<1, 1024, 0, stream>>>(cnt, row_off, N_NODES);
    hipMemsetAsync(cnt, 0, sizeof(int) * N_NODES, stream);
    scatter_kernel<<<(N_EDGES + 255) / 256, 256, 0, stream>>>(src, dst, row_off, cnt, csr_src, N_EDGES);

    // weight / input conversions (transpose + hi/lo split)
    {
        int tot = N_LAYERS * HID * HID;
        wsplit_kernel<<<(tot + 255) / 256, 256, 0, stream>>>(Wq, Wqt_hi, Wqt_lo, HID, HID, HID, tot);
        wsplit_kernel<<<(tot + 255) / 256, 256, 0, stream>>>(Wk, Wkt_hi, Wkt_lo, HID, HID, HID, tot);
        wsplit_kernel<<<(tot + 255) / 256, 256, 0, stream>>>(Wv, Wvt_hi, Wvt_lo, HID, HID, HID, tot);
        int tin = HID * IN_DIM;   // Npad=256, K=128
        wsplit_kernel<<<(tin + 255) / 256, 256, 0, stream>>>(Win, Wint_hi, Wint_lo, IN_DIM, HID, HID, tin);
        int tout = 128 * HID;     // Npad=128, K=256
        wsplit_kernel<<<(tout + 255) / 256, 256, 0, stream>>>(Wout, Wot_hi, Wot_lo, HID, OUT_DIM, 128, tout);
        int tx = MPAD * IN_DIM;
        xsplit_kernel<<<(tx + 255) / 256, 256, 0, stream>>>(X, Xhi, Xlo);
    }

    dim3 blk(256);
    // in_proj: h = X @ Win + bin   -> hi/lo bf16
    gemm_mfma<2><<<dim3(2, MPAD / 128), blk, 0, stream>>>(
        Xhi, Xlo, Wint_hi, Wint_lo, bin_, h_hi, h_lo, IN_DIM, MPAD, HID, HID, 1.f);

    for (int l = 0; l < N_LAYERS; ++l) {
        size_t ws_off = (size_t)l * HID * HID;
        gemm_mfma<1><<<dim3(2, MPAD / 128), blk, 0, stream>>>(
            h_hi, h_lo, Wqt_hi + ws_off, Wqt_lo + ws_off, bq + l * HID, qf, nullptr,
            HID, MPAD, HID, HID, SCALING);
        gemm_mfma<1><<<dim3(2, MPAD / 128), blk, 0, stream>>>(
            h_hi, h_lo, Wkt_hi + ws_off, Wkt_lo + ws_off, bk + l * HID, kf, nullptr,
            HID, MPAD, HID, HID, 1.f);
        gemm_mfma<1><<<dim3(2, MPAD / 128), blk, 0, stream>>>(
            h_hi, h_lo, Wvt_hi + ws_off, Wvt_lo + ws_off, bv + l * HID, vf, nullptr,
            HID, MPAD, HID, HID, 1.f);
        attn_kernel<<<(N_NODES + 3) / 4, blk, 0, stream>>>(
            qf, kf, vf, row_off, csr_src, h_hi, h_lo, N_NODES);
    }
    // out_proj: out = h @ Wout + bout (fp32, guarded store)
    gemm_mfma<0><<<dim3(1, MPAD / 128), blk, 0, stream>>>(
        h_hi, h_lo, Wot_hi, Wot_lo, bout, out, nullptr, HID, N_NODES, OUT_DIM, OUT_DIM, 1.f);
}

// Round 5
// 1599.867 us; speedup vs baseline: 2.9419x; 1.5860x over previous
//
#include <hip/hip_runtime.h>
#include <hip/hip_bf16.h>
#include <hip/hip_fp16.h>

#define N_NODES 50000
#define MPAD    50048            // 391 * 128
#define N_EDGES 800000
#define IN_DIM  128
#define HID     256
#define QKVW    768              // q|k|v concatenated row
#define N_LAYERS 8
#define OUT_DIM 40
#define SCALING 0.17677669529663687f

typedef __attribute__((ext_vector_type(8))) _Float16 f16x8;
typedef __attribute__((ext_vector_type(4))) float f32x4;

__device__ __forceinline__ void gload_lds16(const void* g, void* l) {
    __builtin_amdgcn_global_load_lds(
        (__attribute__((address_space(1))) const unsigned int*)g,
        (__attribute__((address_space(3))) unsigned int*)l, 16, 0, 0);
}

// ---------------- CSR build (by dst) ----------------
__global__ void hist_kernel(const int* __restrict__ dst, int* __restrict__ cnt, int E) {
    int e = blockIdx.x * blockDim.x + threadIdx.x;
    if (e < E) atomicAdd(&cnt[dst[e]], 1);
}

__global__ __launch_bounds__(1024) void scan_kernel(const int* __restrict__ cnt,
                                                    int* __restrict__ row_off, int n) {
    __shared__ int buf[1024];
    __shared__ int carry_s;
    int tid = threadIdx.x;
    if (tid == 0) carry_s = 0;
    __syncthreads();
    for (int base = 0; base < n; base += 1024) {
        int i = base + tid;
        int x = (i < n) ? cnt[i] : 0;
        buf[tid] = x;
        __syncthreads();
        for (int off = 1; off < 1024; off <<= 1) {
            int y = (tid >= off) ? buf[tid - off] : 0;
            __syncthreads();
            buf[tid] += y;
            __syncthreads();
        }
        int carry = carry_s;
        if (i < n) row_off[i] = carry + buf[tid] - x;   // exclusive
        int total = buf[1023];
        __syncthreads();
        if (tid == 0) carry_s = carry + total;
        __syncthreads();
    }
    if (tid == 0) row_off[n] = carry_s;
}

__global__ void scatter_kernel(const int* __restrict__ src, const int* __restrict__ dst,
                               const int* __restrict__ row_off, int* __restrict__ cur,
                               int* __restrict__ csr_src, int E) {
    int e = blockIdx.x * blockDim.x + threadIdx.x;
    if (e < E) {
        int d = dst[e];
        int pos = row_off[d] + atomicAdd(&cur[d], 1);
        csr_src[pos] = src[e];
    }
}

// ---------------- conversion kernels ----------------
// Wq/Wk/Wv [L][256][256] fp32 -> Wqkvt [L][768][256] fp16 (transposed, concatenated)
__global__ void wqkv_cvt_kernel(const float* __restrict__ Wq, const float* __restrict__ Wk,
                                const float* __restrict__ Wv, _Float16* __restrict__ outw) {
    int i = blockIdx.x * blockDim.x + threadIdx.x;
    if (i >= N_LAYERS * QKVW * HID) return;
    int k = i & 255;
    int n = (i >> 8) % QKVW;
    int l = i / (QKVW * HID);
    int seg = n >> 8, nn = n & 255;
    const float* W = (seg == 0) ? Wq : (seg == 1) ? Wk : Wv;
    outw[i] = (_Float16)W[((size_t)l * HID + k) * HID + nn];
}

// Win [128][256] fp32 -> Wint [256][128] fp16 (transposed)
__global__ void win_cvt_kernel(const float* __restrict__ Win, _Float16* __restrict__ outw) {
    int i = blockIdx.x * blockDim.x + threadIdx.x;
    if (i >= HID * IN_DIM) return;
    int k = i & 127;
    int n = i >> 7;
    outw[i] = (_Float16)Win[(size_t)k * HID + n];
}

// Wout [256][40] fp32 -> hi/lo fp16 [128][256] (transposed, padded)
__global__ void wout_cvt_kernel(const float* __restrict__ Wout, _Float16* __restrict__ hi,
                                _Float16* __restrict__ lo) {
    int i = blockIdx.x * blockDim.x + threadIdx.x;
    if (i >= 128 * HID) return;
    int k = i & 255;
    int n = i >> 8;
    float v = (n < OUT_DIM) ? Wout[(size_t)k * OUT_DIM + n] : 0.f;
    _Float16 h = (_Float16)v;
    hi[i] = h;
    lo[i] = (_Float16)(v - (float)h);
}

// X [N_NODES][128] fp32 -> fp16 [MPAD][128] (pad rows zero)
__global__ void x_cvt_kernel(const float* __restrict__ X, _Float16* __restrict__ outx) {
    int i = blockIdx.x * blockDim.x + threadIdx.x;
    if (i >= MPAD * IN_DIM) return;
    int r = i >> 7;
    outx[i] = (_Float16)((r < N_NODES) ? X[i] : 0.f);
}

// ---------------- fp16 1-term MFMA GEMM ----------------
// C[MPAD, Nc] = (A @ B^T + bias)*scale ; A [MPAD][K] f16, B^T [Nc][K] f16, C f16 [MPAD][ldC]
// block 256 (4 waves), tile 128x128, BK=32. Bias/scale chosen per 256-col segment.
__global__ __launch_bounds__(256) void gemm16(
        const _Float16* __restrict__ A, const _Float16* __restrict__ B,
        const float* __restrict__ bias0, const float* __restrict__ bias1,
        const float* __restrict__ bias2, float scale0,
        _Float16* __restrict__ C, int K, int ldC) {
    __shared__ __align__(16) _Float16 lds[2 * 4096];   // A tile 8KB, B tile 8KB
    _Float16* ldsA = lds;
    _Float16* ldsB = lds + 4096;

    const int tid  = threadIdx.x;
    const int lane = tid & 63;
    const int wave = tid >> 6;
    const int row0 = blockIdx.y * 128;
    const int n0   = blockIdx.x * 128;

    // staging: tile [128 rows][32 k] f16 = 512 16B-chunks, linear LDS.
    // chunk p holds k-chunk (p&3)^swz(row), swz(r) = (r&3)^((r>>2)&3) (involution)
    const int p0 = wave * 64 + lane;
    const int p1 = p0 + 256;
    auto srcoff = [&](int p, int grow0) -> size_t {
        int row = p >> 2, cir = p & 3;
        int sw  = (row & 3) ^ ((row >> 2) & 3);
        int sc  = cir ^ sw;
        return (size_t)(grow0 + row) * K + sc * 8;   // element offset
    };
    const size_t offA0 = srcoff(p0, row0), offA1 = srcoff(p1, row0);
    const size_t offB0 = srcoff(p0, n0),   offB1 = srcoff(p1, n0);
    const int d0 = wave * 512;          // f16 offset of this wave's first 1KB dest
    const int d1 = 2048 + wave * 512;

    const int mh = (wave >> 1) * 64;
    const int nh = (wave & 1) * 64;
    int aoff[4], boff[4];
#pragma unroll
    for (int f = 0; f < 4; ++f) {
        int ra = mh + f * 16 + (lane & 15);
        int ca = (lane >> 4) ^ ((ra & 3) ^ ((ra >> 2) & 3));
        aoff[f] = ra * 64 + ca * 16;
        int rb = nh + f * 16 + (lane & 15);
        int cb = (lane >> 4) ^ ((rb & 3) ^ ((rb >> 2) & 3));
        boff[f] = rb * 64 + cb * 16;
    }

    f32x4 acc[4][4];
#pragma unroll
    for (int i = 0; i < 4; ++i)
#pragma unroll
        for (int j = 0; j < 4; ++j) acc[i][j] = {0.f, 0.f, 0.f, 0.f};

    for (int k0 = 0; k0 < K; k0 += 32) {
        gload_lds16(A + offA0 + k0, ldsA + d0);
        gload_lds16(A + offA1 + k0, ldsA + d1);
        gload_lds16(B + offB0 + k0, ldsB + d0);
        gload_lds16(B + offB1 + k0, ldsB + d1);
        __syncthreads();
        f16x8 af[4];
#pragma unroll
        for (int i = 0; i < 4; ++i)
            af[i] = *reinterpret_cast<const f16x8*>(reinterpret_cast<const char*>(ldsA) + aoff[i]);
#pragma unroll
        for (int j = 0; j < 4; ++j) {
            f16x8 bf = *reinterpret_cast<const f16x8*>(reinterpret_cast<const char*>(ldsB) + boff[j]);
#pragma unroll
            for (int i = 0; i < 4; ++i)
                acc[i][j] = __builtin_amdgcn_mfma_f32_16x16x32_f16(af[i], bf, acc[i][j], 0, 0, 0);
        }
        __syncthreads();
    }

    const int seg = n0 >> 8;
    const float* bias = (seg == 0) ? bias0 : (seg == 1) ? bias1 : bias2;
    const float scale = (seg == 0) ? scale0 : 1.f;
    const int fq = lane >> 4;
    const int fr = lane & 15;
#pragma unroll
    for (int i = 0; i < 4; ++i) {
#pragma unroll
        for (int j = 0; j < 4; ++j) {
#pragma unroll
            for (int r = 0; r < 4; ++r) {
                int m = row0 + mh + i * 16 + fq * 4 + r;
                int n = n0 + nh + j * 16 + fr;
                float o = (acc[i][j][r] + bias[n & 255]) * scale;
                C[(size_t)m * ldC + n] = (_Float16)o;
            }
        }
    }
}

// ---------------- out_proj: 2-term fp16 W split, fp32 out, guarded ----------------
__global__ __launch_bounds__(256) void gemm_out(
        const _Float16* __restrict__ A, const _Float16* __restrict__ Bh,
        const _Float16* __restrict__ Bl, const float* __restrict__ bias,
        float* __restrict__ C, int K) {
    __shared__ __align__(16) _Float16 lds[3 * 4096];
    _Float16* ldsA  = lds;
    _Float16* ldsBh = lds + 4096;
    _Float16* ldsBl = lds + 8192;

    const int tid  = threadIdx.x;
    const int lane = tid & 63;
    const int wave = tid >> 6;
    const int row0 = blockIdx.y * 128;

    const int p0 = wave * 64 + lane;
    const int p1 = p0 + 256;
    auto srcoff = [&](int p, int grow0) -> size_t {
        int row = p >> 2, cir = p & 3;
        int sw  = (row & 3) ^ ((row >> 2) & 3);
        int sc  = cir ^ sw;
        return (size_t)(grow0 + row) * K + sc * 8;
    };
    const size_t offA0 = srcoff(p0, row0), offA1 = srcoff(p1, row0);
    const size_t offB0 = srcoff(p0, 0),    offB1 = srcoff(p1, 0);
    const int d0 = wave * 512;
    const int d1 = 2048 + wave * 512;

    const int mh = (wave >> 1) * 64;
    const int nh = (wave & 1) * 64;
    int aoff[4], boff[4];
#pragma unroll
    for (int f = 0; f < 4; ++f) {
        int ra = mh + f * 16 + (lane & 15);
        int ca = (lane >> 4) ^ ((ra & 3) ^ ((ra >> 2) & 3));
        aoff[f] = ra * 64 + ca * 16;
        int rb = nh + f * 16 + (lane & 15);
        int cb = (lane >> 4) ^ ((rb & 3) ^ ((rb >> 2) & 3));
        boff[f] = rb * 64 + cb * 16;
    }

    f32x4 acc[4][4];
#pragma unroll
    for (int i = 0; i < 4; ++i)
#pragma unroll
        for (int j = 0; j < 4; ++j) acc[i][j] = {0.f, 0.f, 0.f, 0.f};

    for (int k0 = 0; k0 < K; k0 += 32) {
        gload_lds16(A + offA0 + k0, ldsA + d0);
        gload_lds16(A + offA1 + k0, ldsA + d1);
        gload_lds16(Bh + offB0 + k0, ldsBh + d0);
        gload_lds16(Bh + offB1 + k0, ldsBh + d1);
        gload_lds16(Bl + offB0 + k0, ldsBl + d0);
        gload_lds16(Bl + offB1 + k0, ldsBl + d1);
        __syncthreads();
        f16x8 af[4];
#pragma unroll
        for (int i = 0; i < 4; ++i)
            af[i] = *reinterpret_cast<const f16x8*>(reinterpret_cast<const char*>(ldsA) + aoff[i]);
#pragma unroll
        for (int j = 0; j < 4; ++j) {
            f16x8 bh = *reinterpret_cast<const f16x8*>(reinterpret_cast<const char*>(ldsBh) + boff[j]);
            f16x8 bl = *reinterpret_cast<const f16x8*>(reinterpret_cast<const char*>(ldsBl) + boff[j]);
#pragma unroll
            for (int i = 0; i < 4; ++i) {
                acc[i][j] = __builtin_amdgcn_mfma_f32_16x16x32_f16(af[i], bh, acc[i][j], 0, 0, 0);
                acc[i][j] = __builtin_amdgcn_mfma_f32_16x16x32_f16(af[i], bl, acc[i][j], 0, 0, 0);
            }
        }
        __syncthreads();
    }

    const int fq = lane >> 4;
    const int fr = lane & 15;
#pragma unroll
    for (int i = 0; i < 4; ++i) {
#pragma unroll
        for (int j = 0; j < 4; ++j) {
#pragma unroll
            for (int r = 0; r < 4; ++r) {
                int m = row0 + mh + i * 16 + fq * 4 + r;
                int n = nh + j * 16 + fr;
                if (m < N_NODES && n < OUT_DIM)
                    C[(size_t)m * OUT_DIM + n] = acc[i][j][r] + bias[n];
            }
        }
    }
}

// ---------------- fused SDDMM + segment-softmax + SpMM ----------------
// one wave per dst node; lane -> head = lane>>3, dims lane*4 .. +4; 4-edge unroll.
// qkv rows: [q(256) | k(256) | v(256)] fp16
__global__ __launch_bounds__(256) void attn_kernel(
        const _Float16* __restrict__ qkv, const int* __restrict__ row_off,
        const int* __restrict__ csr_src, _Float16* __restrict__ h_out, int n) {
    int wave = threadIdx.x >> 6;
    int lane = threadIdx.x & 63;
    int node = blockIdx.x * 4 + wave;
    if (node >= n) return;
    const int loff = lane * 4;
    float4 qv;
    {
        float2 raw = *reinterpret_cast<const float2*>(&qkv[(size_t)node * QKVW + loff]);
        const __half2* h2 = reinterpret_cast<const __half2*>(&raw);
        float2 a = __half22float2(h2[0]), b = __half22float2(h2[1]);
        qv = make_float4(a.x, a.y, b.x, b.y);
    }
    float4 acc = make_float4(0.f, 0.f, 0.f, 0.f);
    float m = -INFINITY, s = 0.f;
    int beg = row_off[node], end = row_off[node + 1];
    int idx = beg;

#define LOAD_KV(slot, sn)                                                                 \
    float2 kr##slot, vr##slot;                                                            \
    {                                                                                     \
        const _Float16* base = qkv + (size_t)(sn) * QKVW;                                 \
        kr##slot = *reinterpret_cast<const float2*>(base + HID + loff);                   \
        vr##slot = *reinterpret_cast<const float2*>(base + 2 * HID + loff);               \
    }

#define DOT(slot, dvar)                                                                   \
    float dvar;                                                                           \
    {                                                                                     \
        const __half2* kh = reinterpret_cast<const __half2*>(&kr##slot);                  \
        float2 k01 = __half22float2(kh[0]), k23 = __half22float2(kh[1]);                  \
        dvar = qv.x * k01.x + qv.y * k01.y + qv.z * k23.x + qv.w * k23.y;                 \
        dvar += __shfl_xor(dvar, 1);                                                      \
        dvar += __shfl_xor(dvar, 2);                                                      \
        dvar += __shfl_xor(dvar, 4);                                                      \
    }

#define VADD(slot, p)                                                                     \
    {                                                                                     \
        const __half2* vh = reinterpret_cast<const __half2*>(&vr##slot);                  \
        float2 v01 = __half22float2(vh[0]), v23 = __half22float2(vh[1]);                  \
        acc.x = fmaf(p, v01.x, acc.x);                                                    \
        acc.y = fmaf(p, v01.y, acc.y);                                                    \
        acc.z = fmaf(p, v23.x, acc.z);                                                    \
        acc.w = fmaf(p, v23.y, acc.w);                                                    \
    }

    for (; idx + 3 < end; idx += 4) {
        int s0 = csr_src[idx], s1 = csr_src[idx + 1];
        int s2 = csr_src[idx + 2], s3 = csr_src[idx + 3];
        LOAD_KV(0, s0) LOAD_KV(1, s1) LOAD_KV(2, s2) LOAD_KV(3, s3)
        DOT(0, e0) DOT(1, e1) DOT(2, e2) DOT(3, e3)
        float mn = fmaxf(fmaxf(fmaxf(m, e0), fmaxf(e1, e2)), e3);
        float c  = __expf(m - mn);
        float p0 = __expf(e0 - mn), p1 = __expf(e1 - mn);
        float p2 = __expf(e2 - mn), p3 = __expf(e3 - mn);
        s = fmaf(s, c, (p0 + p1) + (p2 + p3));
        acc.x *= c; acc.y *= c; acc.z *= c; acc.w *= c;
        VADD(0, p0) VADD(1, p1) VADD(2, p2) VADD(3, p3)
        m = mn;
    }
    for (; idx < end; ++idx) {
        int s0 = csr_src[idx];
        LOAD_KV(0, s0)
        DOT(0, e0)
        float mn = fmaxf(m, e0);
        float c = __expf(m - mn);
        float p0 = __expf(e0 - mn);
        s = fmaf(s, c, p0);
        acc.x *= c; acc.y *= c; acc.z *= c; acc.w *= c;
        VADD(0, p0)
        m = mn;
    }
#undef LOAD_KV
#undef DOT
#undef VADD

    float inv = (s > 0.f) ? 1.f / s : 0.f;
    __half2 o01 = __floats2half2_rn(acc.x * inv, acc.y * inv);
    __half2 o23 = __floats2half2_rn(acc.z * inv, acc.w * inv);
    union { __half2 h2[2]; float2 f2; } u;
    u.h2[0] = o01; u.h2[1] = o23;
    *reinterpret_cast<float2*>(&h_out[(size_t)node * HID + loff]) = u.f2;
}

extern "C" void kernel_launch(void* const* d_in, const int* in_sizes, int n_in,
                              void* d_out, int out_size, void* d_ws, size_t ws_size,
                              hipStream_t stream) {
    const float* X    = (const float*)d_in[0];
    const int*   src  = (const int*)d_in[1];
    const int*   dst  = (const int*)d_in[2];
    const float* Win  = (const float*)d_in[3];
    const float* bin_ = (const float*)d_in[4];
    const float* Wq   = (const float*)d_in[5];
    const float* Wk   = (const float*)d_in[6];
    const float* Wv   = (const float*)d_in[7];
    const float* bq   = (const float*)d_in[8];
    const float* bk   = (const float*)d_in[9];
    const float* bv   = (const float*)d_in[10];
    const float* Wout = (const float*)d_in[11];
    const float* bout = (const float*)d_in[12];
    float* out = (float*)d_out;

    char* ws = (char*)d_ws;
    size_t off = 0;
    auto alloc = [&](size_t bytes) -> void* {
        void* p = ws + off;
        off = (off + bytes + 255) & ~(size_t)255;
        return p;
    };
    _Float16* qkv   = (_Float16*)alloc((size_t)MPAD * QKVW * 2);
    _Float16* h     = (_Float16*)alloc((size_t)MPAD * HID * 2);
    _Float16* Xf    = (_Float16*)alloc((size_t)MPAD * IN_DIM * 2);
    _Float16* Wqkvt = (_Float16*)alloc((size_t)N_LAYERS * QKVW * HID * 2);
    _Float16* Wint  = (_Float16*)alloc((size_t)HID * IN_DIM * 2);
    _Float16* Wot_h = (_Float16*)alloc((size_t)128 * HID * 2);
    _Float16* Wot_l = (_Float16*)alloc((size_t)128 * HID * 2);
    int* cnt     = (int*)alloc(sizeof(int) * N_NODES);
    int* row_off = (int*)alloc(sizeof(int) * (N_NODES + 1));
    int* csr_src = (int*)alloc(sizeof(int) * N_EDGES);

    // CSR build
    hipMemsetAsync(cnt, 0, sizeof(int) * N_NODES, stream);
    hist_kernel<<<(N_EDGES + 255) / 256, 256, 0, stream>>>(dst, cnt, N_EDGES);
    scan_kernel<<<1, 1024, 0, stream>>>(cnt, row_off, N_NODES);
    hipMemsetAsync(cnt, 0, sizeof(int) * N_NODES, stream);
    scatter_kernel<<<(N_EDGES + 255) / 256, 256, 0, stream>>>(src, dst, row_off, cnt, csr_src, N_EDGES);

    // conversions
    {
        int t1 = N_LAYERS * QKVW * HID;
        wqkv_cvt_kernel<<<(t1 + 255) / 256, 256, 0, stream>>>(Wq, Wk, Wv, Wqkvt);
        int t2 = HID * IN_DIM;
        win_cvt_kernel<<<(t2 + 255) / 256, 256, 0, stream>>>(Win, Wint);
        int t3 = 128 * HID;
        wout_cvt_kernel<<<(t3 + 255) / 256, 256, 0, stream>>>(Wout, Wot_h, Wot_l);
        int t4 = MPAD * IN_DIM;
        x_cvt_kernel<<<(t4 + 255) / 256, 256, 0, stream>>>(X, Xf);
    }

    dim3 blk(256);
    // in_proj: h = X @ Win + bin  (fp16 out, ldC=256)
    gemm16<<<dim3(2, MPAD / 128), blk, 0, stream>>>(
        Xf, Wint, bin_, bin_, bin_, 1.f, h, IN_DIM, HID);

    for (int l = 0; l < N_LAYERS; ++l) {
        const _Float16* Bl = Wqkvt + (size_t)l * QKVW * HID;
        // fused QKV: qkv[m][0:768] = (h@Wq+bq)*sc | h@Wk+bk | h@Wv+bv
        gemm16<<<dim3(6, MPAD / 128), blk, 0, stream>>>(
            h, Bl, bq + l * HID, bk + l * HID, bv + l * HID, SCALING, qkv, HID, QKVW);
        attn_kernel<<<(N_NODES + 3) / 4, blk, 0, stream>>>(
            qkv, row_off, csr_src, h, N_NODES);
    }
    // out_proj
    gemm_out<<<dim3(1, MPAD / 128), blk, 0, stream>>>(
        h, Wot_h, Wot_l, bout, out, HID);
}

// Round 6
// 1517.620 us; speedup vs baseline: 3.1013x; 1.0542x over previous
//
#include <hip/hip_runtime.h>
#include <hip/hip_bf16.h>
#include <hip/hip_fp16.h>

#define N_NODES 50000
#define MPAD    50048            // 391 * 128
#define N_EDGES 800000
#define IN_DIM  128
#define HID     256
#define QKVW    768              // q|k|v concatenated row
#define N_LAYERS 8
#define OUT_DIM 40
#define SCALING 0.17677669529663687f

typedef __attribute__((ext_vector_type(8))) _Float16 f16x8;
typedef __attribute__((ext_vector_type(4))) float f32x4;

__device__ __forceinline__ void gload_lds16(const void* g, void* l) {
    __builtin_amdgcn_global_load_lds(
        (__attribute__((address_space(1))) const unsigned int*)g,
        (__attribute__((address_space(3))) unsigned int*)l, 16, 0, 0);
}

// ---------------- CSR build (by dst) ----------------
__global__ void hist_kernel(const int* __restrict__ dst, int* __restrict__ cnt, int E) {
    int e = blockIdx.x * blockDim.x + threadIdx.x;
    if (e < E) atomicAdd(&cnt[dst[e]], 1);
}

// single-block scan, wave-shfl based (4 barriers per 1024-chunk instead of 20)
__global__ __launch_bounds__(1024) void scan_kernel(const int* __restrict__ cnt,
                                                    int* __restrict__ row_off, int n) {
    __shared__ int wsum[16];
    __shared__ int carry_s;
    int tid = threadIdx.x;
    int lane = tid & 63, wid = tid >> 6;
    if (tid == 0) carry_s = 0;
    __syncthreads();
    for (int base = 0; base < n; base += 1024) {
        int i = base + tid;
        int x = (i < n) ? cnt[i] : 0;
        int v = x;
#pragma unroll
        for (int off = 1; off < 64; off <<= 1) {
            int y = __shfl_up(v, off);
            if (lane >= off) v += y;
        }
        if (lane == 63) wsum[wid] = v;
        __syncthreads();
        if (wid == 0) {
            int w = (lane < 16) ? wsum[lane] : 0;
#pragma unroll
            for (int off = 1; off < 16; off <<= 1) {
                int y = __shfl_up(w, off);
                if (lane >= off) w += y;
            }
            if (lane < 16) wsum[lane] = w;   // inclusive wave sums
        }
        __syncthreads();
        int wbase = (wid > 0) ? wsum[wid - 1] : 0;
        int carry = carry_s;
        if (i < n) row_off[i] = carry + wbase + v - x;   // exclusive
        int total = wsum[15];
        __syncthreads();
        if (tid == 0) carry_s = carry + total;
        __syncthreads();
    }
    if (tid == 0) row_off[n] = carry_s;
}

__global__ void scatter_kernel(const int* __restrict__ src, const int* __restrict__ dst,
                               const int* __restrict__ row_off, int* __restrict__ cur,
                               int* __restrict__ csr_src, int E) {
    int e = blockIdx.x * blockDim.x + threadIdx.x;
    if (e < E) {
        int d = dst[e];
        int pos = row_off[d] + atomicAdd(&cur[d], 1);
        csr_src[pos] = src[e];
    }
}

// ---------------- conversion kernels ----------------
__global__ void wqkv_cvt_kernel(const float* __restrict__ Wq, const float* __restrict__ Wk,
                                const float* __restrict__ Wv, _Float16* __restrict__ outw) {
    int i = blockIdx.x * blockDim.x + threadIdx.x;
    if (i >= N_LAYERS * QKVW * HID) return;
    int k = i & 255;
    int n = (i >> 8) % QKVW;
    int l = i / (QKVW * HID);
    int seg = n >> 8, nn = n & 255;
    const float* W = (seg == 0) ? Wq : (seg == 1) ? Wk : Wv;
    outw[i] = (_Float16)W[((size_t)l * HID + k) * HID + nn];
}

__global__ void win_cvt_kernel(const float* __restrict__ Win, _Float16* __restrict__ outw) {
    int i = blockIdx.x * blockDim.x + threadIdx.x;
    if (i >= HID * IN_DIM) return;
    int k = i & 127;
    int n = i >> 7;
    outw[i] = (_Float16)Win[(size_t)k * HID + n];
}

__global__ void wout_cvt_kernel(const float* __restrict__ Wout, _Float16* __restrict__ hi,
                                _Float16* __restrict__ lo) {
    int i = blockIdx.x * blockDim.x + threadIdx.x;
    if (i >= 128 * HID) return;
    int k = i & 255;
    int n = i >> 8;
    float v = (n < OUT_DIM) ? Wout[(size_t)k * OUT_DIM + n] : 0.f;
    _Float16 h = (_Float16)v;
    hi[i] = h;
    lo[i] = (_Float16)(v - (float)h);
}

__global__ void x_cvt_kernel(const float* __restrict__ X, _Float16* __restrict__ outx) {
    int i = blockIdx.x * blockDim.x + threadIdx.x;
    if (i >= MPAD * IN_DIM) return;
    int r = i >> 7;
    outx[i] = (_Float16)((r < N_NODES) ? X[i] : 0.f);
}

// ---------------- fp16 MFMA GEMM, double-buffered LDS + counted vmcnt ----------------
// C[MPAD, Nc] = (A @ B^T + bias)*scale ; A [MPAD][K] f16, B^T [Nc][K] f16, C f16.
// block 256 (4 waves), tile 128x128, BK=32, NT = K/32 tiles. grid: (rows, cols).
template<int NT>
__global__ __launch_bounds__(256) void gemm16(
        const _Float16* __restrict__ A, const _Float16* __restrict__ B,
        const float* __restrict__ bias0, const float* __restrict__ bias1,
        const float* __restrict__ bias2, float scale0,
        _Float16* __restrict__ C, int ldC) {
    __shared__ __align__(16) _Float16 lds[2][2 * 4096];   // [buf][A(8KB) | B(8KB)]
    const int K = NT * 32;

    const int tid  = threadIdx.x;
    const int lane = tid & 63;
    const int wave = tid >> 6;
    const int row0 = blockIdx.x * 128;   // rows fastest: consecutive blocks share B tile
    const int n0   = blockIdx.y * 128;

    // staging: tile [128 rows][32 k] f16 = 512 16B-chunks, linear LDS.
    // chunk p holds k-chunk (p&3)^swz(row), swz(r) = (r&3)^((r>>2)&3) (involution)
    const int p0 = wave * 64 + lane;
    const int p1 = p0 + 256;
    auto srcoff = [&](int p, int grow0) -> size_t {
        int row = p >> 2, cir = p & 3;
        int sw  = (row & 3) ^ ((row >> 2) & 3);
        int sc  = cir ^ sw;
        return (size_t)(grow0 + row) * K + sc * 8;   // element offset
    };
    const size_t offA0 = srcoff(p0, row0), offA1 = srcoff(p1, row0);
    const size_t offB0 = srcoff(p0, n0),   offB1 = srcoff(p1, n0);
    const int d0 = wave * 512;
    const int d1 = 2048 + wave * 512;

    const int mh = (wave >> 1) * 64;
    const int nh = (wave & 1) * 64;
    int aoff[4], boff[4];
#pragma unroll
    for (int f = 0; f < 4; ++f) {
        int ra = mh + f * 16 + (lane & 15);
        int ca = (lane >> 4) ^ ((ra & 3) ^ ((ra >> 2) & 3));
        aoff[f] = ra * 64 + ca * 16;
        int rb = nh + f * 16 + (lane & 15);
        int cb = (lane >> 4) ^ ((rb & 3) ^ ((rb >> 2) & 3));
        boff[f] = rb * 64 + cb * 16;
    }

    f32x4 acc[4][4];
#pragma unroll
    for (int i = 0; i < 4; ++i)
#pragma unroll
        for (int j = 0; j < 4; ++j) acc[i][j] = {0.f, 0.f, 0.f, 0.f};

    auto STAGE = [&](int b, int t) {
        _Float16* LA = &lds[b][0];
        _Float16* LB = &lds[b][4096];
        const size_t k0 = (size_t)t * 32;
        gload_lds16(A + offA0 + k0, LA + d0);
        gload_lds16(A + offA1 + k0, LA + d1);
        gload_lds16(B + offB0 + k0, LB + d0);
        gload_lds16(B + offB1 + k0, LB + d1);
    };

    STAGE(0, 0);
#pragma unroll
    for (int t = 0; t < NT; ++t) {
        const int cur = t & 1;
        if (t + 1 < NT) {
            STAGE(cur ^ 1, t + 1);
            asm volatile("s_waitcnt vmcnt(4)" ::: "memory");   // drain only buf[cur]'s loads
        } else {
            asm volatile("s_waitcnt vmcnt(0)" ::: "memory");
        }
        __builtin_amdgcn_s_barrier();
        const char* baseA = (const char*)&lds[cur][0];
        const char* baseB = (const char*)&lds[cur][4096];
        f16x8 af[4];
#pragma unroll
        for (int i = 0; i < 4; ++i)
            af[i] = *reinterpret_cast<const f16x8*>(baseA + aoff[i]);
#pragma unroll
        for (int j = 0; j < 4; ++j) {
            f16x8 bf = *reinterpret_cast<const f16x8*>(baseB + boff[j]);
#pragma unroll
            for (int i = 0; i < 4; ++i)
                acc[i][j] = __builtin_amdgcn_mfma_f32_16x16x32_f16(af[i], bf, acc[i][j], 0, 0, 0);
        }
        __builtin_amdgcn_s_barrier();   // buf[cur] free for overwrite next iter
    }

    const int seg = n0 >> 8;
    const float* bias = (seg == 0) ? bias0 : (seg == 1) ? bias1 : bias2;
    const float scale = (seg == 0) ? scale0 : 1.f;
    const int fq = lane >> 4;
    const int fr = lane & 15;
#pragma unroll
    for (int i = 0; i < 4; ++i) {
#pragma unroll
        for (int j = 0; j < 4; ++j) {
#pragma unroll
            for (int r = 0; r < 4; ++r) {
                int m = row0 + mh + i * 16 + fq * 4 + r;
                int n = n0 + nh + j * 16 + fr;
                float o = (acc[i][j][r] + bias[n & 255]) * scale;
                C[(size_t)m * ldC + n] = (_Float16)o;
            }
        }
    }
}

// ---------------- out_proj: 2-term fp16 W split, fp32 out, guarded ----------------
__global__ __launch_bounds__(256) void gemm_out(
        const _Float16* __restrict__ A, const _Float16* __restrict__ Bh,
        const _Float16* __restrict__ Bl, const float* __restrict__ bias,
        float* __restrict__ C, int K) {
    __shared__ __align__(16) _Float16 lds[2][3 * 4096];

    const int tid  = threadIdx.x;
    const int lane = tid & 63;
    const int wave = tid >> 6;
    const int row0 = blockIdx.x * 128;

    const int p0 = wave * 64 + lane;
    const int p1 = p0 + 256;
    auto srcoff = [&](int p, int grow0) -> size_t {
        int row = p >> 2, cir = p & 3;
        int sw  = (row & 3) ^ ((row >> 2) & 3);
        int sc  = cir ^ sw;
        return (size_t)(grow0 + row) * K + sc * 8;
    };
    const size_t offA0 = srcoff(p0, row0), offA1 = srcoff(p1, row0);
    const size_t offB0 = srcoff(p0, 0),    offB1 = srcoff(p1, 0);
    const int d0 = wave * 512;
    const int d1 = 2048 + wave * 512;

    const int mh = (wave >> 1) * 64;
    const int nh = (wave & 1) * 64;
    int aoff[4], boff[4];
#pragma unroll
    for (int f = 0; f < 4; ++f) {
        int ra = mh + f * 16 + (lane & 15);
        int ca = (lane >> 4) ^ ((ra & 3) ^ ((ra >> 2) & 3));
        aoff[f] = ra * 64 + ca * 16;
        int rb = nh + f * 16 + (lane & 15);
        int cb = (lane >> 4) ^ ((rb & 3) ^ ((rb >> 2) & 3));
        boff[f] = rb * 64 + cb * 16;
    }

    f32x4 acc[4][4];
#pragma unroll
    for (int i = 0; i < 4; ++i)
#pragma unroll
        for (int j = 0; j < 4; ++j) acc[i][j] = {0.f, 0.f, 0.f, 0.f};

    auto STAGE = [&](int b, int t) {
        _Float16* LA  = &lds[b][0];
        _Float16* LBh = &lds[b][4096];
        _Float16* LBl = &lds[b][8192];
        const size_t k0 = (size_t)t * 32;
        gload_lds16(A  + offA0 + k0, LA  + d0);
        gload_lds16(A  + offA1 + k0, LA  + d1);
        gload_lds16(Bh + offB0 + k0, LBh + d0);
        gload_lds16(Bh + offB1 + k0, LBh + d1);
        gload_lds16(Bl + offB0 + k0, LBl + d0);
        gload_lds16(Bl + offB1 + k0, LBl + d1);
    };

    STAGE(0, 0);
#pragma unroll
    for (int t = 0; t < 8; ++t) {
        const int cur = t & 1;
        if (t + 1 < 8) {
            STAGE(cur ^ 1, t + 1);
            asm volatile("s_waitcnt vmcnt(6)" ::: "memory");
        } else {
            asm volatile("s_waitcnt vmcnt(0)" ::: "memory");
        }
        __builtin_amdgcn_s_barrier();
        const char* baseA  = (const char*)&lds[cur][0];
        const char* baseBh = (const char*)&lds[cur][4096];
        const char* baseBl = (const char*)&lds[cur][8192];
        f16x8 af[4];
#pragma unroll
        for (int i = 0; i < 4; ++i)
            af[i] = *reinterpret_cast<const f16x8*>(baseA + aoff[i]);
#pragma unroll
        for (int j = 0; j < 4; ++j) {
            f16x8 bh = *reinterpret_cast<const f16x8*>(baseBh + boff[j]);
            f16x8 bl = *reinterpret_cast<const f16x8*>(baseBl + boff[j]);
#pragma unroll
            for (int i = 0; i < 4; ++i) {
                acc[i][j] = __builtin_amdgcn_mfma_f32_16x16x32_f16(af[i], bh, acc[i][j], 0, 0, 0);
                acc[i][j] = __builtin_amdgcn_mfma_f32_16x16x32_f16(af[i], bl, acc[i][j], 0, 0, 0);
            }
        }
        __builtin_amdgcn_s_barrier();
    }

    const int fq = lane >> 4;
    const int fr = lane & 15;
#pragma unroll
    for (int i = 0; i < 4; ++i) {
#pragma unroll
        for (int j = 0; j < 4; ++j) {
#pragma unroll
            for (int r = 0; r < 4; ++r) {
                int m = row0 + mh + i * 16 + fq * 4 + r;
                int n = nh + j * 16 + fr;
                if (m < N_NODES && n < OUT_DIM)
                    C[(size_t)m * OUT_DIM + n] = acc[i][j][r] + bias[n];
            }
        }
    }
}

// ---------------- fused SDDMM + segment-softmax + SpMM ----------------
// one wave per dst node; lane -> head = lane>>3, dims lane*4 .. +4; 4-edge unroll.
// qkv rows: [q(256) | k(256) | v(256)] fp16
__global__ __launch_bounds__(256) void attn_kernel(
        const _Float16* __restrict__ qkv, const int* __restrict__ row_off,
        const int* __restrict__ csr_src, _Float16* __restrict__ h_out, int n) {
    int wave = threadIdx.x >> 6;
    int lane = threadIdx.x & 63;
    int node = blockIdx.x * 4 + wave;
    if (node >= n) return;
    const int loff = lane * 4;
    float4 qv;
    {
        float2 raw = *reinterpret_cast<const float2*>(&qkv[(size_t)node * QKVW + loff]);
        const __half2* h2 = reinterpret_cast<const __half2*>(&raw);
        float2 a = __half22float2(h2[0]), b = __half22float2(h2[1]);
        qv = make_float4(a.x, a.y, b.x, b.y);
    }
    float4 acc = make_float4(0.f, 0.f, 0.f, 0.f);
    float m = -INFINITY, s = 0.f;
    int beg = row_off[node], end = row_off[node + 1];
    int idx = beg;

#define LOAD_KV(slot, sn)                                                                 \
    float2 kr##slot, vr##slot;                                                            \
    {                                                                                     \
        const _Float16* base = qkv + (size_t)(sn) * QKVW;                                 \
        kr##slot = *reinterpret_cast<const float2*>(base + HID + loff);                   \
        vr##slot = *reinterpret_cast<const float2*>(base + 2 * HID + loff);               \
    }

#define DOT(slot, dvar)                                                                   \
    float dvar;                                                                           \
    {                                                                                     \
        const __half2* kh = reinterpret_cast<const __half2*>(&kr##slot);                  \
        float2 k01 = __half22float2(kh[0]), k23 = __half22float2(kh[1]);                  \
        dvar = qv.x * k01.x + qv.y * k01.y + qv.z * k23.x + qv.w * k23.y;                 \
        dvar += __shfl_xor(dvar, 1);                                                      \
        dvar += __shfl_xor(dvar, 2);                                                      \
        dvar += __shfl_xor(dvar, 4);                                                      \
    }

#define VADD(slot, p)                                                                     \
    {                                                                                     \
        const __half2* vh = reinterpret_cast<const __half2*>(&vr##slot);                  \
        float2 v01 = __half22float2(vh[0]), v23 = __half22float2(vh[1]);                  \
        acc.x = fmaf(p, v01.x, acc.x);                                                    \
        acc.y = fmaf(p, v01.y, acc.y);                                                    \
        acc.z = fmaf(p, v23.x, acc.z);                                                    \
        acc.w = fmaf(p, v23.y, acc.w);                                                    \
    }

    for (; idx + 3 < end; idx += 4) {
        int s0 = csr_src[idx], s1 = csr_src[idx + 1];
        int s2 = csr_src[idx + 2], s3 = csr_src[idx + 3];
        LOAD_KV(0, s0) LOAD_KV(1, s1) LOAD_KV(2, s2) LOAD_KV(3, s3)
        DOT(0, e0) DOT(1, e1) DOT(2, e2) DOT(3, e3)
        float mn = fmaxf(fmaxf(fmaxf(m, e0), fmaxf(e1, e2)), e3);
        float c  = __expf(m - mn);
        float p0 = __expf(e0 - mn), p1 = __expf(e1 - mn);
        float p2 = __expf(e2 - mn), p3 = __expf(e3 - mn);
        s = fmaf(s, c, (p0 + p1) + (p2 + p3));
        acc.x *= c; acc.y *= c; acc.z *= c; acc.w *= c;
        VADD(0, p0) VADD(1, p1) VADD(2, p2) VADD(3, p3)
        m = mn;
    }
    for (; idx < end; ++idx) {
        int s0 = csr_src[idx];
        LOAD_KV(0, s0)
        DOT(0, e0)
        float mn = fmaxf(m, e0);
        float c = __expf(m - mn);
        float p0 = __expf(e0 - mn);
        s = fmaf(s, c, p0);
        acc.x *= c; acc.y *= c; acc.z *= c; acc.w *= c;
        VADD(0, p0)
        m = mn;
    }
#undef LOAD_KV
#undef DOT
#undef VADD

    float inv = (s > 0.f) ? 1.f / s : 0.f;
    __half2 o01 = __floats2half2_rn(acc.x * inv, acc.y * inv);
    __half2 o23 = __floats2half2_rn(acc.z * inv, acc.w * inv);
    union { __half2 h2[2]; float2 f2; } u;
    u.h2[0] = o01; u.h2[1] = o23;
    *reinterpret_cast<float2*>(&h_out[(size_t)node * HID + loff]) = u.f2;
}

extern "C" void kernel_launch(void* const* d_in, const int* in_sizes, int n_in,
                              void* d_out, int out_size, void* d_ws, size_t ws_size,
                              hipStream_t stream) {
    const float* X    = (const float*)d_in[0];
    const int*   src  = (const int*)d_in[1];
    const int*   dst  = (const int*)d_in[2];
    const float* Win  = (const float*)d_in[3];
    const float* bin_ = (const float*)d_in[4];
    const float* Wq   = (const float*)d_in[5];
    const float* Wk   = (const float*)d_in[6];
    const float* Wv   = (const float*)d_in[7];
    const float* bq   = (const float*)d_in[8];
    const float* bk   = (const float*)d_in[9];
    const float* bv   = (const float*)d_in[10];
    const float* Wout = (const float*)d_in[11];
    const float* bout = (const float*)d_in[12];
    float* out = (float*)d_out;

    char* ws = (char*)d_ws;
    size_t off = 0;
    auto alloc = [&](size_t bytes) -> void* {
        void* p = ws + off;
        off = (off + bytes + 255) & ~(size_t)255;
        return p;
    };
    _Float16* qkv   = (_Float16*)alloc((size_t)MPAD * QKVW * 2);
    _Float16* h     = (_Float16*)alloc((size_t)MPAD * HID * 2);
    _Float16* Xf    = (_Float16*)alloc((size_t)MPAD * IN_DIM * 2);
    _Float16* Wqkvt = (_Float16*)alloc((size_t)N_LAYERS * QKVW * HID * 2);
    _Float16* Wint  = (_Float16*)alloc((size_t)HID * IN_DIM * 2);
    _Float16* Wot_h = (_Float16*)alloc((size_t)128 * HID * 2);
    _Float16* Wot_l = (_Float16*)alloc((size_t)128 * HID * 2);
    int* cnt     = (int*)alloc(sizeof(int) * N_NODES);
    int* row_off = (int*)alloc(sizeof(int) * (N_NODES + 1));
    int* csr_src = (int*)alloc(sizeof(int) * N_EDGES);

    // CSR build
    hipMemsetAsync(cnt, 0, sizeof(int) * N_NODES, stream);
    hist_kernel<<<(N_EDGES + 255) / 256, 256, 0, stream>>>(dst, cnt, N_EDGES);
    scan_kernel<<<1, 1024, 0, stream>>>(cnt, row_off, N_NODES);
    hipMemsetAsync(cnt, 0, sizeof(int) * N_NODES, stream);
    scatter_kernel<<<(N_EDGES + 255) / 256, 256, 0, stream>>>(src, dst, row_off, cnt, csr_src, N_EDGES);

    // conversions
    {
        int t1 = N_LAYERS * QKVW * HID;
        wqkv_cvt_kernel<<<(t1 + 255) / 256, 256, 0, stream>>>(Wq, Wk, Wv, Wqkvt);
        int t2 = HID * IN_DIM;
        win_cvt_kernel<<<(t2 + 255) / 256, 256, 0, stream>>>(Win, Wint);
        int t3 = 128 * HID;
        wout_cvt_kernel<<<(t3 + 255) / 256, 256, 0, stream>>>(Wout, Wot_h, Wot_l);
        int t4 = MPAD * IN_DIM;
        x_cvt_kernel<<<(t4 + 255) / 256, 256, 0, stream>>>(X, Xf);
    }

    dim3 blk(256);
    // in_proj: h = X @ Win + bin  (fp16 out, ldC=256), K=128 -> NT=4
    gemm16<4><<<dim3(MPAD / 128, 2), blk, 0, stream>>>(
        Xf, Wint, bin_, bin_, bin_, 1.f, h, HID);

    for (int l = 0; l < N_LAYERS; ++l) {
        const _Float16* Bl = Wqkvt + (size_t)l * QKVW * HID;
        // fused QKV: qkv[m][0:768] = (h@Wq+bq)*sc | h@Wk+bk | h@Wv+bv ; K=256 -> NT=8
        gemm16<8><<<dim3(MPAD / 128, 6), blk, 0, stream>>>(
            h, Bl, bq + l * HID, bk + l * HID, bv + l * HID, SCALING, qkv, QKVW);
        attn_kernel<<<(N_NODES + 3) / 4, blk, 0, stream>>>(
            qkv, row_off, csr_src, h, N_NODES);
    }
    // out_proj
    gemm_out<<<dim3(MPAD / 128, 1), blk, 0, stream>>>(
        h, Wot_h, Wot_l, bout, out, HID);
}

// Round 7
// 1434.530 us; speedup vs baseline: 3.2809x; 1.0579x over previous
//
#include <hip/hip_runtime.h>
#include <hip/hip_bf16.h>
#include <hip/hip_fp16.h>

#define N_NODES 50000
#define MPAD    50048            // 391 * 128
#define NRB     391              // MPAD/128 row-blocks
#define N_EDGES 800000
#define IN_DIM  128
#define HID     256
#define QKVW    768              // q|k|v concatenated row
#define N_LAYERS 8
#define OUT_DIM 40
#define SCALING 0.17677669529663687f

typedef __attribute__((ext_vector_type(8))) _Float16 f16x8;
typedef __attribute__((ext_vector_type(4))) float f32x4;

__device__ __forceinline__ void gload_lds16(const void* g, void* l) {
    __builtin_amdgcn_global_load_lds(
        (__attribute__((address_space(1))) const unsigned int*)g,
        (__attribute__((address_space(3))) unsigned int*)l, 16, 0, 0);
}

// ---------------- CSR build (by dst) ----------------
__global__ void hist_kernel(const int* __restrict__ dst, int* __restrict__ cnt, int E) {
    int e = blockIdx.x * blockDim.x + threadIdx.x;
    if (e < E) atomicAdd(&cnt[dst[e]], 1);
}

// single-block scan, wave-shfl based
__global__ __launch_bounds__(1024) void scan_kernel(const int* __restrict__ cnt,
                                                    int* __restrict__ row_off, int n) {
    __shared__ int wsum[16];
    __shared__ int carry_s;
    int tid = threadIdx.x;
    int lane = tid & 63, wid = tid >> 6;
    if (tid == 0) carry_s = 0;
    __syncthreads();
    for (int base = 0; base < n; base += 1024) {
        int i = base + tid;
        int x = (i < n) ? cnt[i] : 0;
        int v = x;
#pragma unroll
        for (int off = 1; off < 64; off <<= 1) {
            int y = __shfl_up(v, off);
            if (lane >= off) v += y;
        }
        if (lane == 63) wsum[wid] = v;
        __syncthreads();
        if (wid == 0) {
            int w = (lane < 16) ? wsum[lane] : 0;
#pragma unroll
            for (int off = 1; off < 16; off <<= 1) {
                int y = __shfl_up(w, off);
                if (lane >= off) w += y;
            }
            if (lane < 16) wsum[lane] = w;   // inclusive wave sums
        }
        __syncthreads();
        int wbase = (wid > 0) ? wsum[wid - 1] : 0;
        int carry = carry_s;
        if (i < n) row_off[i] = carry + wbase + v - x;   // exclusive
        int total = wsum[15];
        __syncthreads();
        if (tid == 0) carry_s = carry + total;
        __syncthreads();
    }
    if (tid == 0) row_off[n] = carry_s;
}

__global__ void scatter_kernel(const int* __restrict__ src, const int* __restrict__ dst,
                               const int* __restrict__ row_off, int* __restrict__ cur,
                               int* __restrict__ csr_src, int E) {
    int e = blockIdx.x * blockDim.x + threadIdx.x;
    if (e < E) {
        int d = dst[e];
        int pos = row_off[d] + atomicAdd(&cur[d], 1);
        csr_src[pos] = src[e];
    }
}

// ---------------- conversion kernels ----------------
__global__ void wqkv_cvt_kernel(const float* __restrict__ Wq, const float* __restrict__ Wk,
                                const float* __restrict__ Wv, _Float16* __restrict__ outw) {
    int i = blockIdx.x * blockDim.x + threadIdx.x;
    if (i >= N_LAYERS * QKVW * HID) return;
    int k = i & 255;
    int n = (i >> 8) % QKVW;
    int l = i / (QKVW * HID);
    int seg = n >> 8, nn = n & 255;
    const float* W = (seg == 0) ? Wq : (seg == 1) ? Wk : Wv;
    outw[i] = (_Float16)W[((size_t)l * HID + k) * HID + nn];
}

__global__ void win_cvt_kernel(const float* __restrict__ Win, _Float16* __restrict__ outw) {
    int i = blockIdx.x * blockDim.x + threadIdx.x;
    if (i >= HID * IN_DIM) return;
    int k = i & 127;
    int n = i >> 7;
    outw[i] = (_Float16)Win[(size_t)k * HID + n];
}

__global__ void wout_cvt_kernel(const float* __restrict__ Wout, _Float16* __restrict__ hi,
                                _Float16* __restrict__ lo) {
    int i = blockIdx.x * blockDim.x + threadIdx.x;
    if (i >= 128 * HID) return;
    int k = i & 255;
    int n = i >> 8;
    float v = (n < OUT_DIM) ? Wout[(size_t)k * OUT_DIM + n] : 0.f;
    _Float16 h = (_Float16)v;
    hi[i] = h;
    lo[i] = (_Float16)(v - (float)h);
}

__global__ void x_cvt_kernel(const float* __restrict__ X, _Float16* __restrict__ outx) {
    int i = blockIdx.x * blockDim.x + threadIdx.x;
    if (i >= MPAD * IN_DIM) return;
    int r = i >> 7;
    outx[i] = (_Float16)((r < N_NODES) ? X[i] : 0.f);
}

// ---------------- fp16 MFMA GEMM, dbuf + counted vmcnt + XCD-clustered tiles ----------
// C[MPAD, Nc] = (A @ B^T + bias)*scale ; A [MPAD][K] f16, B^T [Nc][K] f16, C f16.
// block 256 (4 waves), tile 128x128, BK=32, NT = K/32 tiles, NCOLT col-tiles.
// 1-D grid of 8*NCOLT*ceil(NRB/8): b=(q*NCOLT+j)*8+x -> row=q*8+x, col=j.
// All NCOLT col-tiles of a row share (b&7) => same XCD under round-robin dispatch,
// so the A-tile is fetched into that XCD's L2 once and reused NCOLT times.
template<int NT, int NCOLT>
__global__ __launch_bounds__(256) void gemm16(
        const _Float16* __restrict__ A, const _Float16* __restrict__ B,
        const float* __restrict__ bias0, const float* __restrict__ bias1,
        const float* __restrict__ bias2, float scale0,
        _Float16* __restrict__ C, int ldC) {
    __shared__ __align__(16) _Float16 lds[2][2 * 4096];   // [buf][A(8KB) | B(8KB)]
    const int K = NT * 32;

    const int bb = blockIdx.x;
    const int xx = bb & 7, tt = bb >> 3;
    const int qq = tt / NCOLT, jj = tt - qq * NCOLT;
    const int rowblk = qq * 8 + xx;
    if (rowblk >= NRB) return;
    const int row0 = rowblk * 128;
    const int n0   = jj * 128;

    const int tid  = threadIdx.x;
    const int lane = tid & 63;
    const int wave = tid >> 6;

    // staging: tile [128 rows][32 k] f16 = 512 16B-chunks, linear LDS.
    // chunk p holds k-chunk (p&3)^swz(row), swz(r) = (r&3)^((r>>2)&3) (involution)
    const int p0 = wave * 64 + lane;
    const int p1 = p0 + 256;
    auto srcoff = [&](int p, int grow0) -> size_t {
        int row = p >> 2, cir = p & 3;
        int sw  = (row & 3) ^ ((row >> 2) & 3);
        int sc  = cir ^ sw;
        return (size_t)(grow0 + row) * K + sc * 8;   // element offset
    };
    const size_t offA0 = srcoff(p0, row0), offA1 = srcoff(p1, row0);
    const size_t offB0 = srcoff(p0, n0),   offB1 = srcoff(p1, n0);
    const int d0 = wave * 512;
    const int d1 = 2048 + wave * 512;

    const int mh = (wave >> 1) * 64;
    const int nh = (wave & 1) * 64;
    int aoff[4], boff[4];
#pragma unroll
    for (int f = 0; f < 4; ++f) {
        int ra = mh + f * 16 + (lane & 15);
        int ca = (lane >> 4) ^ ((ra & 3) ^ ((ra >> 2) & 3));
        aoff[f] = ra * 64 + ca * 16;
        int rb = nh + f * 16 + (lane & 15);
        int cb = (lane >> 4) ^ ((rb & 3) ^ ((rb >> 2) & 3));
        boff[f] = rb * 64 + cb * 16;
    }

    f32x4 acc[4][4];
#pragma unroll
    for (int i = 0; i < 4; ++i)
#pragma unroll
        for (int j = 0; j < 4; ++j) acc[i][j] = {0.f, 0.f, 0.f, 0.f};

    auto STAGE = [&](int b, int t) {
        _Float16* LA = &lds[b][0];
        _Float16* LB = &lds[b][4096];
        const size_t k0 = (size_t)t * 32;
        gload_lds16(A + offA0 + k0, LA + d0);
        gload_lds16(A + offA1 + k0, LA + d1);
        gload_lds16(B + offB0 + k0, LB + d0);
        gload_lds16(B + offB1 + k0, LB + d1);
    };

    STAGE(0, 0);
#pragma unroll
    for (int t = 0; t < NT; ++t) {
        const int cur = t & 1;
        if (t + 1 < NT) {
            STAGE(cur ^ 1, t + 1);
            asm volatile("s_waitcnt vmcnt(4)" ::: "memory");   // drain only buf[cur]'s loads
        } else {
            asm volatile("s_waitcnt vmcnt(0)" ::: "memory");
        }
        __builtin_amdgcn_s_barrier();
        const char* baseA = (const char*)&lds[cur][0];
        const char* baseB = (const char*)&lds[cur][4096];
        f16x8 af[4];
#pragma unroll
        for (int i = 0; i < 4; ++i)
            af[i] = *reinterpret_cast<const f16x8*>(baseA + aoff[i]);
#pragma unroll
        for (int j = 0; j < 4; ++j) {
            f16x8 bf = *reinterpret_cast<const f16x8*>(baseB + boff[j]);
#pragma unroll
            for (int i = 0; i < 4; ++i)
                acc[i][j] = __builtin_amdgcn_mfma_f32_16x16x32_f16(af[i], bf, acc[i][j], 0, 0, 0);
        }
        __builtin_amdgcn_s_barrier();   // buf[cur] free for overwrite next iter
    }

    const int seg = n0 >> 8;
    const float* bias = (seg == 0) ? bias0 : (seg == 1) ? bias1 : bias2;
    const float scale = (seg == 0) ? scale0 : 1.f;
    const int fq = lane >> 4;
    const int fr = lane & 15;
#pragma unroll
    for (int i = 0; i < 4; ++i) {
#pragma unroll
        for (int j = 0; j < 4; ++j) {
#pragma unroll
            for (int r = 0; r < 4; ++r) {
                int m = row0 + mh + i * 16 + fq * 4 + r;
                int n = n0 + nh + j * 16 + fr;
                float o = (acc[i][j][r] + bias[n & 255]) * scale;
                C[(size_t)m * ldC + n] = (_Float16)o;
            }
        }
    }
}

// ---------------- out_proj: 2-term fp16 W split, fp32 out, guarded ----------------
__global__ __launch_bounds__(256) void gemm_out(
        const _Float16* __restrict__ A, const _Float16* __restrict__ Bh,
        const _Float16* __restrict__ Bl, const float* __restrict__ bias,
        float* __restrict__ C, int K) {
    __shared__ __align__(16) _Float16 lds[2][3 * 4096];

    const int tid  = threadIdx.x;
    const int lane = tid & 63;
    const int wave = tid >> 6;
    const int row0 = blockIdx.x * 128;

    const int p0 = wave * 64 + lane;
    const int p1 = p0 + 256;
    auto srcoff = [&](int p, int grow0) -> size_t {
        int row = p >> 2, cir = p & 3;
        int sw  = (row & 3) ^ ((row >> 2) & 3);
        int sc  = cir ^ sw;
        return (size_t)(grow0 + row) * K + sc * 8;
    };
    const size_t offA0 = srcoff(p0, row0), offA1 = srcoff(p1, row0);
    const size_t offB0 = srcoff(p0, 0),    offB1 = srcoff(p1, 0);
    const int d0 = wave * 512;
    const int d1 = 2048 + wave * 512;

    const int mh = (wave >> 1) * 64;
    const int nh = (wave & 1) * 64;
    int aoff[4], boff[4];
#pragma unroll
    for (int f = 0; f < 4; ++f) {
        int ra = mh + f * 16 + (lane & 15);
        int ca = (lane >> 4) ^ ((ra & 3) ^ ((ra >> 2) & 3));
        aoff[f] = ra * 64 + ca * 16;
        int rb = nh + f * 16 + (lane & 15);
        int cb = (lane >> 4) ^ ((rb & 3) ^ ((rb >> 2) & 3));
        boff[f] = rb * 64 + cb * 16;
    }

    f32x4 acc[4][4];
#pragma unroll
    for (int i = 0; i < 4; ++i)
#pragma unroll
        for (int j = 0; j < 4; ++j) acc[i][j] = {0.f, 0.f, 0.f, 0.f};

    auto STAGE = [&](int b, int t) {
        _Float16* LA  = &lds[b][0];
        _Float16* LBh = &lds[b][4096];
        _Float16* LBl = &lds[b][8192];
        const size_t k0 = (size_t)t * 32;
        gload_lds16(A  + offA0 + k0, LA  + d0);
        gload_lds16(A  + offA1 + k0, LA  + d1);
        gload_lds16(Bh + offB0 + k0, LBh + d0);
        gload_lds16(Bh + offB1 + k0, LBh + d1);
        gload_lds16(Bl + offB0 + k0, LBl + d0);
        gload_lds16(Bl + offB1 + k0, LBl + d1);
    };

    STAGE(0, 0);
#pragma unroll
    for (int t = 0; t < 8; ++t) {
        const int cur = t & 1;
        if (t + 1 < 8) {
            STAGE(cur ^ 1, t + 1);
            asm volatile("s_waitcnt vmcnt(6)" ::: "memory");
        } else {
            asm volatile("s_waitcnt vmcnt(0)" ::: "memory");
        }
        __builtin_amdgcn_s_barrier();
        const char* baseA  = (const char*)&lds[cur][0];
        const char* baseBh = (const char*)&lds[cur][4096];
        const char* baseBl = (const char*)&lds[cur][8192];
        f16x8 af[4];
#pragma unroll
        for (int i = 0; i < 4; ++i)
            af[i] = *reinterpret_cast<const f16x8*>(baseA + aoff[i]);
#pragma unroll
        for (int j = 0; j < 4; ++j) {
            f16x8 bh = *reinterpret_cast<const f16x8*>(baseBh + boff[j]);
            f16x8 bl = *reinterpret_cast<const f16x8*>(baseBl + boff[j]);
#pragma unroll
            for (int i = 0; i < 4; ++i) {
                acc[i][j] = __builtin_amdgcn_mfma_f32_16x16x32_f16(af[i], bh, acc[i][j], 0, 0, 0);
                acc[i][j] = __builtin_amdgcn_mfma_f32_16x16x32_f16(af[i], bl, acc[i][j], 0, 0, 0);
            }
        }
        __builtin_amdgcn_s_barrier();
    }

    const int fq = lane >> 4;
    const int fr = lane & 15;
#pragma unroll
    for (int i = 0; i < 4; ++i) {
#pragma unroll
        for (int j = 0; j < 4; ++j) {
#pragma unroll
            for (int r = 0; r < 4; ++r) {
                int m = row0 + mh + i * 16 + fq * 4 + r;
                int n = nh + j * 16 + fr;
                if (m < N_NODES && n < OUT_DIM)
                    C[(size_t)m * OUT_DIM + n] = acc[i][j][r] + bias[n];
            }
        }
    }
}

// ---------------- fused SDDMM + segment-softmax + SpMM ----------------
// one wave per dst node; lane -> head = lane>>3, dims lane*4 .. +4.
// 2-deep software pipeline over 4-edge groups (issue g+1 loads before processing g).
__device__ __forceinline__ float edot(const float4& qv, const float2& kr) {
    const __half2* kh = reinterpret_cast<const __half2*>(&kr);
    float2 k01 = __half22float2(kh[0]), k23 = __half22float2(kh[1]);
    float d = qv.x * k01.x + qv.y * k01.y + qv.z * k23.x + qv.w * k23.y;
    d += __shfl_xor(d, 1);
    d += __shfl_xor(d, 2);
    d += __shfl_xor(d, 4);
    return d;
}
__device__ __forceinline__ void vadd(float4& acc, float p, const float2& vr) {
    const __half2* vh = reinterpret_cast<const __half2*>(&vr);
    float2 v01 = __half22float2(vh[0]), v23 = __half22float2(vh[1]);
    acc.x = fmaf(p, v01.x, acc.x);
    acc.y = fmaf(p, v01.y, acc.y);
    acc.z = fmaf(p, v23.x, acc.z);
    acc.w = fmaf(p, v23.y, acc.w);
}

__global__ __launch_bounds__(256) void attn_kernel(
        const _Float16* __restrict__ qkv, const int* __restrict__ row_off,
        const int* __restrict__ csr_src, _Float16* __restrict__ h_out, int n) {
    int wave = threadIdx.x >> 6;
    int lane = threadIdx.x & 63;
    int node = blockIdx.x * 4 + wave;
    if (node >= n) return;
    const int loff = lane * 4;
    float4 qv;
    {
        float2 raw = *reinterpret_cast<const float2*>(&qkv[(size_t)node * QKVW + loff]);
        const __half2* h2 = reinterpret_cast<const __half2*>(&raw);
        float2 a = __half22float2(h2[0]), b = __half22float2(h2[1]);
        qv = make_float4(a.x, a.y, b.x, b.y);
    }
    float4 acc = make_float4(0.f, 0.f, 0.f, 0.f);
    float m = -INFINITY, s = 0.f;
    int beg = row_off[node], end = row_off[node + 1];
    int idx = beg;

    float2 kA0, kA1, kA2, kA3, vA0, vA1, vA2, vA3;
    float2 kB0, kB1, kB2, kB3, vB0, vB1, vB2, vB3;

#define ISSUE(S, i0)                                                                      \
    {                                                                                     \
        int t0 = csr_src[(i0)], t1 = csr_src[(i0) + 1];                                   \
        int t2 = csr_src[(i0) + 2], t3 = csr_src[(i0) + 3];                               \
        const _Float16* b0 = qkv + (size_t)t0 * QKVW;                                     \
        const _Float16* b1 = qkv + (size_t)t1 * QKVW;                                     \
        const _Float16* b2 = qkv + (size_t)t2 * QKVW;                                     \
        const _Float16* b3 = qkv + (size_t)t3 * QKVW;                                     \
        k##S##0 = *(const float2*)(b0 + HID + loff);                                      \
        v##S##0 = *(const float2*)(b0 + 2 * HID + loff);                                  \
        k##S##1 = *(const float2*)(b1 + HID + loff);                                      \
        v##S##1 = *(const float2*)(b1 + 2 * HID + loff);                                  \
        k##S##2 = *(const float2*)(b2 + HID + loff);                                      \
        v##S##2 = *(const float2*)(b2 + 2 * HID + loff);                                  \
        k##S##3 = *(const float2*)(b3 + HID + loff);                                      \
        v##S##3 = *(const float2*)(b3 + 2 * HID + loff);                                  \
    }

#define PROCESS(S)                                                                        \
    {                                                                                     \
        float e0 = edot(qv, k##S##0), e1 = edot(qv, k##S##1);                             \
        float e2 = edot(qv, k##S##2), e3 = edot(qv, k##S##3);                             \
        float mn = fmaxf(fmaxf(fmaxf(m, e0), fmaxf(e1, e2)), e3);                         \
        float c  = __expf(m - mn);                                                        \
        float p0 = __expf(e0 - mn), p1 = __expf(e1 - mn);                                 \
        float p2 = __expf(e2 - mn), p3 = __expf(e3 - mn);                                 \
        s = fmaf(s, c, (p0 + p1) + (p2 + p3));                                            \
        acc.x *= c; acc.y *= c; acc.z *= c; acc.w *= c;                                   \
        vadd(acc, p0, v##S##0); vadd(acc, p1, v##S##1);                                   \
        vadd(acc, p2, v##S##2); vadd(acc, p3, v##S##3);                                   \
        m = mn;                                                                           \
    }

    if (idx + 3 < end) {
        ISSUE(A, idx);
        while (true) {
            int nxt = idx + 4;
            bool haveB = (nxt + 3 < end);
            if (haveB) ISSUE(B, nxt);
            PROCESS(A);
            idx = nxt;
            if (!haveB) break;
            nxt = idx + 4;
            bool haveA = (nxt + 3 < end);
            if (haveA) ISSUE(A, nxt);
            PROCESS(B);
            idx = nxt;
            if (!haveA) break;
        }
    }
    // scalar tail (<4 edges)
    for (; idx < end; ++idx) {
        int s0 = csr_src[idx];
        const _Float16* base = qkv + (size_t)s0 * QKVW;
        float2 kr = *(const float2*)(base + HID + loff);
        float2 vr = *(const float2*)(base + 2 * HID + loff);
        float e0 = edot(qv, kr);
        float mn = fmaxf(m, e0);
        float c = __expf(m - mn);
        float p0 = __expf(e0 - mn);
        s = fmaf(s, c, p0);
        acc.x *= c; acc.y *= c; acc.z *= c; acc.w *= c;
        vadd(acc, p0, vr);
        m = mn;
    }
#undef ISSUE
#undef PROCESS

    float inv = (s > 0.f) ? 1.f / s : 0.f;
    __half2 o01 = __floats2half2_rn(acc.x * inv, acc.y * inv);
    __half2 o23 = __floats2half2_rn(acc.z * inv, acc.w * inv);
    union { __half2 h2[2]; float2 f2; } u;
    u.h2[0] = o01; u.h2[1] = o23;
    *reinterpret_cast<float2*>(&h_out[(size_t)node * HID + loff]) = u.f2;
}

extern "C" void kernel_launch(void* const* d_in, const int* in_sizes, int n_in,
                              void* d_out, int out_size, void* d_ws, size_t ws_size,
                              hipStream_t stream) {
    const float* X    = (const float*)d_in[0];
    const int*   src  = (const int*)d_in[1];
    const int*   dst  = (const int*)d_in[2];
    const float* Win  = (const float*)d_in[3];
    const float* bin_ = (const float*)d_in[4];
    const float* Wq   = (const float*)d_in[5];
    const float* Wk   = (const float*)d_in[6];
    const float* Wv   = (const float*)d_in[7];
    const float* bq   = (const float*)d_in[8];
    const float* bk   = (const float*)d_in[9];
    const float* bv   = (const float*)d_in[10];
    const float* Wout = (const float*)d_in[11];
    const float* bout = (const float*)d_in[12];
    float* out = (float*)d_out;

    char* ws = (char*)d_ws;
    size_t off = 0;
    auto alloc = [&](size_t bytes) -> void* {
        void* p = ws + off;
        off = (off + bytes + 255) & ~(size_t)255;
        return p;
    };
    _Float16* qkv   = (_Float16*)alloc((size_t)MPAD * QKVW * 2);
    _Float16* h     = (_Float16*)alloc((size_t)MPAD * HID * 2);
    _Float16* Xf    = (_Float16*)alloc((size_t)MPAD * IN_DIM * 2);
    _Float16* Wqkvt = (_Float16*)alloc((size_t)N_LAYERS * QKVW * HID * 2);
    _Float16* Wint  = (_Float16*)alloc((size_t)HID * IN_DIM * 2);
    _Float16* Wot_h = (_Float16*)alloc((size_t)128 * HID * 2);
    _Float16* Wot_l = (_Float16*)alloc((size_t)128 * HID * 2);
    int* cnt     = (int*)alloc(sizeof(int) * N_NODES);
    int* row_off = (int*)alloc(sizeof(int) * (N_NODES + 1));
    int* csr_src = (int*)alloc(sizeof(int) * N_EDGES);

    // CSR build
    hipMemsetAsync(cnt, 0, sizeof(int) * N_NODES, stream);
    hist_kernel<<<(N_EDGES + 255) / 256, 256, 0, stream>>>(dst, cnt, N_EDGES);
    scan_kernel<<<1, 1024, 0, stream>>>(cnt, row_off, N_NODES);
    hipMemsetAsync(cnt, 0, sizeof(int) * N_NODES, stream);
    scatter_kernel<<<(N_EDGES + 255) / 256, 256, 0, stream>>>(src, dst, row_off, cnt, csr_src, N_EDGES);

    // conversions
    {
        int t1 = N_LAYERS * QKVW * HID;
        wqkv_cvt_kernel<<<(t1 + 255) / 256, 256, 0, stream>>>(Wq, Wk, Wv, Wqkvt);
        int t2 = HID * IN_DIM;
        win_cvt_kernel<<<(t2 + 255) / 256, 256, 0, stream>>>(Win, Wint);
        int t3 = 128 * HID;
        wout_cvt_kernel<<<(t3 + 255) / 256, 256, 0, stream>>>(Wout, Wot_h, Wot_l);
        int t4 = MPAD * IN_DIM;
        x_cvt_kernel<<<(t4 + 255) / 256, 256, 0, stream>>>(X, Xf);
    }

    dim3 blk(256);
    const int NQ = 8 * ((NRB + 7) / 8);   // 392 row-slots
    // in_proj: h = X @ Win + bin  (fp16 out, ldC=256), K=128 -> NT=4, 2 col-tiles
    gemm16<4, 2><<<dim3(NQ * 2), blk, 0, stream>>>(
        Xf, Wint, bin_, bin_, bin_, 1.f, h, HID);

    for (int l = 0; l < N_LAYERS; ++l) {
        const _Float16* Bl = Wqkvt + (size_t)l * QKVW * HID;
        // fused QKV: qkv[m][0:768] = (h@Wq+bq)*sc | h@Wk+bk | h@Wv+bv ; K=256 -> NT=8
        gemm16<8, 6><<<dim3(NQ * 6), blk, 0, stream>>>(
            h, Bl, bq + l * HID, bk + l * HID, bv + l * HID, SCALING, qkv, QKVW);
        attn_kernel<<<(N_NODES + 3) / 4, blk, 0, stream>>>(
            qkv, row_off, csr_src, h, N_NODES);
    }
    // out_proj
    gemm_out<<<dim3(NRB), blk, 0, stream>>>(
        h, Wot_h, Wot_l, bout, out, HID);
}